// Round 1
// 583.706 us; speedup vs baseline: 1.1269x; 1.1269x over previous
//
#include <hip/hip_runtime.h>

// Problem dims
constexpr int Bn = 64;     // batch
constexpr int Dn = 512;    // embed dim
constexpr int Mn = 1024;   // M
constexpr int Ln = 256;    // L
constexpr int Kn = 30;     // K heads
constexpr int KP = 32;     // K padded to 32 rows

typedef __attribute__((ext_vector_type(4))) float f32x4;
typedef __attribute__((ext_vector_type(2))) float f32x2;
typedef __attribute__((ext_vector_type(4))) unsigned int u32x4;
typedef __attribute__((ext_vector_type(8))) _Float16 f16x8;
typedef unsigned short ushort_t;

// ---------------------------------------------------------------------------
// fp32 -> fp16 hi/lo split (x*s = hi + lo, each fp16; ~22 effective mantissa
// bits). Packs two consecutive elements into one u32 per plane.
// ---------------------------------------------------------------------------
__device__ __forceinline__ void cvt_pair(float x0, float x1, float s,
                                         unsigned int& hpack,
                                         unsigned int& lpack)
{
    float a = x0 * s, b = x1 * s;
    _Float16 ha = (_Float16)a, hb = (_Float16)b;
    _Float16 la = (_Float16)(a - (float)ha), lb = (_Float16)(b - (float)hb);
    hpack = (unsigned int)__builtin_bit_cast(ushort_t, ha) |
            ((unsigned int)__builtin_bit_cast(ushort_t, hb) << 16);
    lpack = (unsigned int)__builtin_bit_cast(ushort_t, la) |
            ((unsigned int)__builtin_bit_cast(ushort_t, lb) << 16);
}

__device__ __forceinline__ void cvt_one(float x, float s, ushort_t& h, ushort_t& l)
{
    float a = x * s;
    _Float16 ha = (_Float16)a;
    _Float16 la = (_Float16)(a - (float)ha);
    h = __builtin_bit_cast(ushort_t, ha);
    l = __builtin_bit_cast(ushort_t, la);
}

// ---------------------------------------------------------------------------
// Unified split-fp16 MFMA GEMM.
//   C[b][M][N] = alpha * (A*scaleA) @ (B*scaleB)   with
//     NN (BT=false): B[b] is [K][N] row-major, row stride ldB
//     NT (BT=true):  B[b] is [N][K] row-major, row stride ldB
//   A[b] is [M][K] row-major, row stride ldA. Rows >= Mreal read as 0.
//   BM = MT*16, BN = 64, BK = 32. 256 threads = 4 waves; wave w owns cols
//   [w*16, w*16+16). grid: (Ndim/64, ceil(M/BM), batches).
//   mfma_f32_16x16x32_f16: A k = (lane>>4)*8+j, row = lane&15;
//                          C/D col = lane&15, row = (lane>>4)*4+r.
//   Each product = 3 MFMAs: Ah*Bh + Al*Bh + Ah*Bl (Al*Bl ~2^-22, dropped).
// ---------------------------------------------------------------------------
template <int MT, bool BT>
__global__ __launch_bounds__(256) void fgemm_kernel(
    const float* __restrict__ A, const float* __restrict__ B,
    float* __restrict__ C,
    int Mreal, int Ndim, int Kdim, int ldA, int ldB,
    long sA, long sB, long sC,
    float scaleA, float scaleB, float alpha)
{
    constexpr int BM = MT * 16;
    constexpr int AP = 20;                      // u32 pitch: 16 data + 4 pad
    constexpr int ASZ = BM * AP;                // one A plane
    constexpr int BP_NN = 66;                   // NN packed pitch (64 + 2 pad)
    constexpr int BSZ = BT ? (2 * 64 * AP) : (32 * BP_NN);
    __shared__ unsigned int smem[2 * ASZ + BSZ];
    unsigned int* Ah = smem;
    unsigned int* Al = smem + ASZ;
    unsigned int* Bh = smem + 2 * ASZ;          // BT planes
    unsigned int* Bl = Bh + 64 * AP;
    unsigned int* Bp = smem + 2 * ASZ;          // NN packed lo|hi

    const int t  = threadIdx.x;
    const int n0 = blockIdx.x * 64;
    const int m0 = blockIdx.y * BM;
    const int b  = blockIdx.z;
    const float* Ab = A + (long)b * sA;
    const float* Bb = B + (long)b * sB;
    float* Cb = C + (long)b * sC;

    const int lane = t & 63, w = t >> 6;
    const int fr = lane & 15, g = lane >> 4;

    const int kp  = t & 15, r16 = t >> 4;       // 16 threads per row staging
    const int nn  = t & 63, kr  = t >> 6;       // NN B staging

    f32x4 acc[MT];
    #pragma unroll
    for (int i = 0; i < MT; i++) acc[i] = (f32x4){0.f, 0.f, 0.f, 0.f};

    for (int k0 = 0; k0 < Kdim; k0 += 32) {
        __syncthreads();
        // ---- stage A (BM x 32) as hi/lo planes, convert in flight ----
        #pragma unroll
        for (int i = 0; i < MT; i++) {
            int m = r16 + 16 * i;
            int gm = m0 + m;
            float x0 = 0.f, x1 = 0.f;
            if (gm < Mreal) {
                f32x2 v = *(const f32x2*)&Ab[(long)gm * ldA + k0 + 2 * kp];
                x0 = v.x; x1 = v.y;
            }
            unsigned int hp, lp;
            cvt_pair(x0, x1, scaleA, hp, lp);
            Ah[m * AP + kp] = hp;
            Al[m * AP + kp] = lp;
        }
        // ---- stage B ----
        if constexpr (BT) {
            #pragma unroll
            for (int i = 0; i < 4; i++) {
                int nrow = r16 + 16 * i;
                f32x2 v = *(const f32x2*)&Bb[(long)(n0 + nrow) * ldB + k0 + 2 * kp];
                unsigned int hp, lp;
                cvt_pair(v.x, v.y, scaleB, hp, lp);
                Bh[nrow * AP + kp] = hp;
                Bl[nrow * AP + kp] = lp;
            }
        } else {
            #pragma unroll
            for (int i = 0; i < 8; i++) {
                int kk = kr + 4 * i;
                float x = Bb[(long)(k0 + kk) * ldB + n0 + nn];
                ushort_t h, l;
                cvt_one(x, scaleB, h, l);
                Bp[kk * BP_NN + nn] = (unsigned int)l | ((unsigned int)h << 16);
            }
        }
        __syncthreads();

        // ---- fragments ----
        f16x8 fah[MT], fal[MT];
        #pragma unroll
        for (int mt = 0; mt < MT; mt++) {
            int row = fr + 16 * mt;
            fah[mt] = __builtin_bit_cast(f16x8, *(const u32x4*)&Ah[row * AP + g * 4]);
            fal[mt] = __builtin_bit_cast(f16x8, *(const u32x4*)&Al[row * AP + g * 4]);
        }
        f16x8 fbh, fbl;
        if constexpr (BT) {
            int row = w * 16 + fr;
            fbh = __builtin_bit_cast(f16x8, *(const u32x4*)&Bh[row * AP + g * 4]);
            fbl = __builtin_bit_cast(f16x8, *(const u32x4*)&Bl[row * AP + g * 4]);
        } else {
            unsigned int p[8];
            #pragma unroll
            for (int j = 0; j < 8; j++)
                p[j] = Bp[(g * 8 + j) * BP_NN + w * 16 + fr];
            unsigned int hu[4], lu[4];
            #pragma unroll
            for (int r = 0; r < 4; r++) {
                hu[r] = __builtin_amdgcn_perm(p[2 * r + 1], p[2 * r], 0x07060302u);
                lu[r] = __builtin_amdgcn_perm(p[2 * r + 1], p[2 * r], 0x05040100u);
            }
            fbh = __builtin_bit_cast(f16x8, (u32x4){hu[0], hu[1], hu[2], hu[3]});
            fbl = __builtin_bit_cast(f16x8, (u32x4){lu[0], lu[1], lu[2], lu[3]});
        }

        #pragma unroll
        for (int mt = 0; mt < MT; mt++) {
            acc[mt] = __builtin_amdgcn_mfma_f32_16x16x32_f16(fah[mt], fbh, acc[mt], 0, 0, 0);
            acc[mt] = __builtin_amdgcn_mfma_f32_16x16x32_f16(fal[mt], fbh, acc[mt], 0, 0, 0);
            acc[mt] = __builtin_amdgcn_mfma_f32_16x16x32_f16(fah[mt], fbl, acc[mt], 0, 0, 0);
        }
    }

    #pragma unroll
    for (int mt = 0; mt < MT; mt++) {
        #pragma unroll
        for (int r = 0; r < 4; r++) {
            int row = m0 + mt * 16 + g * 4 + r;
            Cb[(long)row * Ndim + n0 + w * 16 + fr] = acc[mt][r] * alpha;
        }
    }
}

// ---------------------------------------------------------------------------
// reduce KS slabs: out[i] = Sum_s in[s*slab + i], n % 4 == 0  (poolq partials)
// ---------------------------------------------------------------------------
__global__ void reduce_slabs_kernel(const float* __restrict__ in,
                                    float* __restrict__ out,
                                    long n, int ks, long slab)
{
    long i = ((long)blockIdx.x * blockDim.x + threadIdx.x) * 4;
    if (i < n) {
        f32x4 s = *(const f32x4*)(in + i);
        for (int r = 1; r < ks; r++) {
            f32x4 v = *(const f32x4*)(in + (long)r * slab + i);
            s.x += v.x; s.y += v.y; s.z += v.z; s.w += v.w;
        }
        *(f32x4*)(out + i) = s;
    }
}

// ---------------------------------------------------------------------------
// Sa[b][64][512]: rows 0-29 = W_v, 30-31 = 0, 32-63 = P[b] rows 0-31
// ---------------------------------------------------------------------------
__global__ void build_sa_kernel(const float* __restrict__ Wv,
                                const float* __restrict__ P,
                                float* __restrict__ Sa)
{
    const int b = blockIdx.x, t = threadIdx.x;
    for (int idx = t; idx < 64 * 512; idx += 256) {
        int row = idx >> 9, col = idx & 511;
        float v;
        if (row < 30)      v = Wv[(long)row * Dn + col];
        else if (row < 32) v = 0.f;
        else               v = P[((long)b * KP + row - 32) * Dn + col];
        Sa[((long)b * 64 + row) * Dn + col] = v;
    }
}

// ---------------------------------------------------------------------------
// sv[b,m] = Sum_k whv[k] * tanh(Sout[b][k][m] + Sout[b][32+k][m])
// ---------------------------------------------------------------------------
__global__ void sv_kernel(const float* __restrict__ Sout,
                          const float* __restrict__ whv,
                          float* __restrict__ sv)
{
    const int mc = blockIdx.x, b = blockIdx.y, t = threadIdx.x;
    const int m = mc * 256 + t;
    const float* Sb = Sout + (long)b * 64 * Mn;
    float s = 0.f;
    #pragma unroll
    for (int k = 0; k < Kn; k++)
        s += whv[k] * tanhf(Sb[(long)k * Mn + m] + Sb[(long)(32 + k) * Mn + m]);
    sv[(long)b * Mn + m] = s;
}

// ---------------------------------------------------------------------------
// sq[b,l] = Sum_k whq[k] * tanh(WqQ[b][k][l] + Tq[b][k][l])
// ---------------------------------------------------------------------------
__global__ void sq_kernel(const float* __restrict__ WqQ,
                          const float* __restrict__ Tq,
                          const float* __restrict__ whq,
                          float* __restrict__ sq)
{
    const int b = blockIdx.x, l = threadIdx.x;
    const float* Wb_ = WqQ + (long)b * KP * Ln;
    const float* Tb  = Tq  + (long)b * KP * Ln;
    float s = 0.f;
    #pragma unroll
    for (int k = 0; k < Kn; k++)
        s += whq[k] * tanhf(Wb_[(long)k * Ln + l] + Tb[(long)k * Ln + l]);
    sq[(long)b * Ln + l] = s;
}

// ---------------------------------------------------------------------------
// pure softmax over logits s[b][COLS] -> a[b][COLS]
// ---------------------------------------------------------------------------
template <int COLS>
__global__ void softmax2_kernel(const float* __restrict__ s, float* __restrict__ a)
{
    const int b = blockIdx.x;
    const int m = threadIdx.x;
    float x = s[(long)b * COLS + m];

    __shared__ float red[COLS / 64];
    __shared__ float bcastv;
    const int wid = m >> 6, lane = m & 63;

    float v = x;
    #pragma unroll
    for (int off = 32; off > 0; off >>= 1) v = fmaxf(v, __shfl_down(v, off, 64));
    if (lane == 0) red[wid] = v;
    __syncthreads();
    if (m == 0) {
        float mx = red[0];
        for (int i = 1; i < COLS / 64; i++) mx = fmaxf(mx, red[i]);
        bcastv = mx;
    }
    __syncthreads();
    const float e = expf(x - bcastv);
    v = e;
    #pragma unroll
    for (int off = 32; off > 0; off >>= 1) v += __shfl_down(v, off, 64);
    if (lane == 0) red[wid] = v;
    __syncthreads();
    if (m == 0) {
        float sm = 0.f;
        for (int i = 0; i < COLS / 64; i++) sm += red[i];
        bcastv = sm;
    }
    __syncthreads();
    a[(long)b * COLS + m] = e / bcastv;
}

// ---------------------------------------------------------------------------
// v1[b,e] = Sum_m a_v[b,m] * V[b,e,m]   (wave per (b,e))
// ---------------------------------------------------------------------------
__global__ __launch_bounds__(64) void poolv_kernel(
    const float* __restrict__ a_v, const float* __restrict__ V,
    float* __restrict__ v1)
{
    const int e = blockIdx.x, b = blockIdx.y;
    const int lane = threadIdx.x;
    const float* vrow = V + ((long)b * Dn + e) * Mn;
    const float* av = a_v + (long)b * Mn;
    float acc = 0.f;
    #pragma unroll
    for (int i = 0; i < 16; i++) acc += vrow[lane + i * 64] * av[lane + i * 64];
    #pragma unroll
    for (int off = 32; off > 0; off >>= 1) acc += __shfl_down(acc, off, 64);
    if (lane == 0) v1[(long)b * Dn + e] = acc;
}

// ---------------------------------------------------------------------------
// poolq partials: pq[ls][b][e] = Sum_{l in ls-chunk} a_q[b,l] * Q[b,l,e]
// ---------------------------------------------------------------------------
__global__ __launch_bounds__(512) void poolq_kernel(
    const float* __restrict__ a_q, const float* __restrict__ Q,
    float* __restrict__ pq)
{
    const int ls = blockIdx.x, b = blockIdx.y, e = threadIdx.x;
    const float* aq = a_q + (long)b * Ln;
    float acc = 0.f;
    for (int l = ls * 64; l < ls * 64 + 64; l++)
        acc += aq[l] * Q[((long)b * Ln + l) * Dn + e];
    pq[((long)ls * Bn + b) * Dn + e] = acc;
}

// ---------------------------------------------------------------------------
// Broadcast outputs
// ---------------------------------------------------------------------------
__global__ void bcast_kernel(const float* __restrict__ v1,
                             const float* __restrict__ q1,
                             float* __restrict__ out)
{
    const long nv4 = (long)Bn * Mn * Dn / 4;
    const long nq4 = (long)Bn * Ln * Dn / 4;
    long idx = (long)blockIdx.x * blockDim.x + threadIdx.x;
    float4* o4 = (float4*)out;
    if (idx < nv4) {
        long fidx = idx * 4;
        int e4 = (int)(fidx & (Dn - 1));
        long bm = fidx >> 9;
        int b = (int)(bm >> 10);
        o4[idx] = *(const float4*)(v1 + (long)b * Dn + e4);
    } else if (idx < nv4 + nq4) {
        long fidx = (idx - nv4) * 4;
        int e4 = (int)(fidx & (Dn - 1));
        long bl = fidx >> 9;
        int b = (int)(bl >> 8);
        o4[idx] = *(const float4*)(q1 + (long)b * Dn + e4);
    }
}

// ---------------------------------------------------------------------------

extern "C" void kernel_launch(void* const* d_in, const int* in_sizes, int n_in,
                              void* d_out, int out_size, void* d_ws, size_t ws_size,
                              hipStream_t stream)
{
    const float* V    = (const float*)d_in[0];  // [B, d, M]
    const float* Q    = (const float*)d_in[1];  // [B, L, d]
    const float* W_b  = (const float*)d_in[2];  // [d, d]
    const float* W_v  = (const float*)d_in[3];  // [K, d]
    const float* W_q  = (const float*)d_in[4];  // [K, d]
    const float* w_hv = (const float*)d_in[5];  // [K, 1]
    const float* w_hq = (const float*)d_in[6];  // [K, 1]
    float* out = (float*)d_out;

    // sizes (floats)
    const long szWqQ = (long)Bn * KP * Ln;   // 524288
    const long szU   = (long)Bn * KP * Dn;   // 1048576
    const long szSa  = (long)Bn * 64 * Dn;   // 2097152
    const long szSo  = (long)Bn * 64 * Mn;   // 4194304

    float* ws   = (float*)d_ws;
    float* WqQ  = ws;                      // szWqQ
    float* U    = WqQ + szWqQ;             // szU
    float* P    = U   + szU;               // szU
    float* Sa   = P   + szU;               // szSa
    float* Sout = Sa  + szSa;              // szSo
    float* R    = Sout + szSo;             // szU
    float* G    = R   + szU;               // szU
    float* Tq   = G   + szU;               // szWqQ
    float* pq   = Tq  + szWqQ;             // 4 * Bn * Dn
    float* sv   = pq  + 4L * Bn * Dn;
    float* sq   = sv  + (long)Bn * Mn;
    float* a_v  = sq  + (long)Bn * Ln;
    float* a_q  = a_v + (long)Bn * Mn;
    float* v1   = a_q + (long)Bn * Ln;
    float* q1   = v1  + (long)Bn * Dn;

    // 1. WqQ[b,k,l] = Wq @ Q[b]^T : NT, M=30, N=256, K=512
    fgemm_kernel<2, true><<<dim3(Ln / 64, 1, Bn), 256, 0, stream>>>(
        W_q, Q, WqQ, Kn, Ln, Dn, Dn, Dn,
        0, (long)Ln * Dn, (long)KP * Ln, 1024.f, 64.f, 1.f / 65536.f);

    // 2. U[b] = WqQ[b] @ Q[b] : NN, M=32, N=512, K=256
    fgemm_kernel<2, false><<<dim3(Dn / 64, 1, Bn), 256, 0, stream>>>(
        WqQ, Q, U, KP, Dn, Ln, Ln, Dn,
        (long)KP * Ln, (long)Ln * Dn, (long)KP * Dn, 256.f, 64.f, 1.f / 16384.f);

    // 3. P = Uflat[2048,512] @ W_b : NN
    fgemm_kernel<4, false><<<dim3(Dn / 64, Bn * KP / 64, 1), 256, 0, stream>>>(
        U, W_b, P, Bn * KP, Dn, Dn, Dn, Dn,
        0, 0, 0, 16.f, 1024.f, 1.f / 16384.f);

    // 4. Sa = [W_v; 0; P[b]]  (64 rows per b)
    build_sa_kernel<<<Bn, 256, 0, stream>>>(W_v, P, Sa);

    // 5. Sout[b] = Sa[b] @ V[b] : NN, M=64, N=1024, K=512
    fgemm_kernel<4, false><<<dim3(Mn / 64, 1, Bn), 256, 0, stream>>>(
        Sa, V, Sout, 64, Mn, Dn, Dn, Mn,
        (long)64 * Dn, (long)Dn * Mn, (long)64 * Mn, 32.f, 64.f, 1.f / 2048.f);

    // 6. sv[b,m] = Sum_k whv[k] tanh(WvV + Tv)
    sv_kernel<<<dim3(Mn / 256, Bn), 256, 0, stream>>>(Sout, w_hv, sv);

    // 7. R[b,k,e] = Sum_m Sout[k,m] V[e,m] : NT, M=32, N=512, K=1024
    fgemm_kernel<2, true><<<dim3(Dn / 64, 1, Bn), 256, 0, stream>>>(
        Sout, V, R, KP, Dn, Mn, Mn, Mn,
        (long)64 * Mn, (long)Dn * Mn, (long)KP * Dn, 256.f, 64.f, 1.f / 16384.f);

    // 8. G = Rflat[2048,512] @ W_b^T : NT
    fgemm_kernel<4, true><<<dim3(Dn / 64, Bn * KP / 64, 1), 256, 0, stream>>>(
        R, W_b, G, Bn * KP, Dn, Dn, Dn, Dn,
        0, 0, 0, 4.f, 1024.f, 1.f / 4096.f);

    // 9. Tq[b,k,l] = Sum_e G[k,e] Q[l,e] : NT, M=32, N=256, K=512
    fgemm_kernel<2, true><<<dim3(Ln / 64, 1, Bn), 256, 0, stream>>>(
        G, Q, Tq, KP, Ln, Dn, Dn, Dn,
        (long)KP * Dn, (long)Ln * Dn, (long)KP * Ln, 4.f, 64.f, 1.f / 256.f);

    // 10. sq[b,l] = Sum_k whq[k] tanh(WqQ + Tq)
    sq_kernel<<<Bn, Ln, 0, stream>>>(WqQ, Tq, w_hq, sq);

    // 11. softmaxes
    softmax2_kernel<Mn><<<Bn, Mn, 0, stream>>>(sv, a_v);
    softmax2_kernel<Ln><<<Bn, Ln, 0, stream>>>(sq, a_q);

    // 12. pooling
    poolv_kernel<<<dim3(Dn, Bn), 64, 0, stream>>>(a_v, V, v1);
    poolq_kernel<<<dim3(4, Bn), Dn, 0, stream>>>(a_q, Q, pq);
    reduce_slabs_kernel<<<(int)((long)Bn * Dn / 4 / 256), 256, 0, stream>>>(
        pq, q1, (long)Bn * Dn, 4, (long)Bn * Dn);

    // 13. broadcast outputs
    {
        long n4 = (long)Bn * Mn * Dn / 4 + (long)Bn * Ln * Dn / 4;
        bcast_kernel<<<(int)((n4 + 255) / 256), 256, 0, stream>>>(v1, q1, out);
    }
}

// Round 3
// 494.575 us; speedup vs baseline: 1.3300x; 1.1802x over previous
//
#include <hip/hip_runtime.h>

// Problem dims
constexpr int Bn = 64;     // batch
constexpr int Dn = 512;    // embed dim
constexpr int Mn = 1024;   // M
constexpr int Ln = 256;    // L
constexpr int Kn = 30;     // K heads
constexpr int KP = 32;     // K padded to 32 rows

typedef __attribute__((ext_vector_type(4))) float f32x4;
typedef __attribute__((ext_vector_type(2))) float f32x2;
typedef __attribute__((ext_vector_type(4))) unsigned int u32x4;
typedef __attribute__((ext_vector_type(8))) _Float16 f16x8;
typedef __attribute__((ext_vector_type(2))) _Float16 f16x2;
typedef unsigned short ushort_t;

// ---------------------------------------------------------------------------
// fp32 -> fp16 hi/lo split (x = hi + lo, each fp16; ~22 effective mantissa
// bits). No pre-scale: all operands/intermediates are well inside fp16
// normal range (max ~4e3 << 65504); lo underflow to subnormal is benign.
// ---------------------------------------------------------------------------
__device__ __forceinline__ void cvt_pair(float a, float b,
                                         unsigned int& hp, unsigned int& lp)
{
    _Float16 ha = (_Float16)a, hb = (_Float16)b;
    _Float16 la = (_Float16)(a - (float)ha), lb = (_Float16)(b - (float)hb);
    f16x2 hv = {ha, hb}, lv = {la, lb};
    hp = __builtin_bit_cast(unsigned int, hv);
    lp = __builtin_bit_cast(unsigned int, lv);
}

__device__ __forceinline__ unsigned int cvt_one_pack(float x)
{
    _Float16 h = (_Float16)x;
    _Float16 l = (_Float16)(x - (float)h);
    return (unsigned int)__builtin_bit_cast(ushort_t, l) |
           ((unsigned int)__builtin_bit_cast(ushort_t, h) << 16);
}

// ---------------------------------------------------------------------------
// Unified split-fp16 MFMA GEMM, 2-stage software pipelined.
//   C[b][M][N] = (A) @ (B)  with
//     NN (BT=false): B[b] is [K][N] row-major, row stride ldB
//     NT (BT=true):  B[b] is [N][K] row-major, row stride ldB
//   A[b] is [M][K] row-major, row stride ldA. Rows >= Mreal read as 0.
//   BM = MT*16, BN = 64, BK = 32. 256 threads = 4 waves; wave w owns cols
//   [w*16, w*16+16). grid: (Ndim/64, ceil(M/BM), batches).
//   Pipeline: stage tile t+1 global->regs BEFORE computing tile t from LDS;
//   convert+ds_write after the barrier (hides HBM latency under MFMA).
//   EPI: 0 = plain C write
//        1 = SAMAP: flat row gr -> Sa row (gr>>5)*64 + 32 + (gr&31)
//        2 = SV   : write rows<32 of C; sv[b,col] = sum_k w[k]*tanh(acc_k +
//                   acc_{k+32}) via shfl reduce  (requires MT=4)
//        3 = SQ   : no C write; sq[b,col] = sum_k w[k]*tanh(X[k,col]+acc_k)
//                   (requires MT=2; sC = X batch stride)
// ---------------------------------------------------------------------------
template <int MT, bool BT, int EPI>
__global__ __launch_bounds__(256) void fgemm_kernel(
    const float* __restrict__ A, const float* __restrict__ B,
    float* __restrict__ C,
    const float* __restrict__ Wvec, const float* __restrict__ Xadd,
    float* __restrict__ Yout,
    int Mreal, int Ndim, int Kdim, int ldA, int ldB,
    long sA, long sB, long sC)
{
    constexpr int BM = MT * 16;
    constexpr int AP = 20;                      // u32 pitch: 16 data + 4 pad
    constexpr int ASZ = BM * AP;                // one A plane
    constexpr int BP_NN = 66;                   // NN packed pitch (64 + 2 pad)
    constexpr int BSZ = BT ? (2 * 64 * AP) : (32 * BP_NN);
    __shared__ unsigned int smem[2 * ASZ + BSZ];
    __shared__ float wsh[32];
    unsigned int* Ah = smem;
    unsigned int* Al = smem + ASZ;
    unsigned int* Bh = smem + 2 * ASZ;          // BT planes
    unsigned int* Bl = Bh + 64 * AP;
    unsigned int* Bp = smem + 2 * ASZ;          // NN packed lo|hi

    const int t  = threadIdx.x;
    const int n0 = blockIdx.x * 64;
    const int m0 = blockIdx.y * BM;
    const int b  = blockIdx.z;
    const float* Ab = A + (long)b * sA;
    const float* Bb = B + (long)b * sB;

    const int lane = t & 63, w = t >> 6;
    const int fr = lane & 15, g = lane >> 4;
    const int kp  = t & 15, r16 = t >> 4;       // 16 threads per row staging
    const int nn  = t & 63, kr  = t >> 6;       // NN B staging

    if (EPI >= 2 && t < 32) wsh[t] = (t < Kn) ? Wvec[t] : 0.f;

    float as[MT][2];
    float bsv[8];

    auto stageA = [&](int k0) {
        #pragma unroll
        for (int i = 0; i < MT; i++) {
            int gm = m0 + r16 + 16 * i;
            float x0 = 0.f, x1 = 0.f;
            if (gm < Mreal) {
                f32x2 v = *(const f32x2*)&Ab[(long)gm * ldA + k0 + 2 * kp];
                x0 = v.x; x1 = v.y;
            }
            as[i][0] = x0; as[i][1] = x1;
        }
    };
    auto stageB = [&](int k0) {
        if constexpr (BT) {
            #pragma unroll
            for (int i = 0; i < 4; i++) {
                f32x2 v = *(const f32x2*)&Bb[(long)(n0 + r16 + 16 * i) * ldB + k0 + 2 * kp];
                bsv[2 * i] = v.x; bsv[2 * i + 1] = v.y;
            }
        } else {
            #pragma unroll
            for (int i = 0; i < 8; i++)
                bsv[i] = Bb[(long)(k0 + kr + 4 * i) * ldB + n0 + nn];
        }
    };
    auto storeStage = [&]() {
        #pragma unroll
        for (int i = 0; i < MT; i++) {
            unsigned int hp, lp;
            cvt_pair(as[i][0], as[i][1], hp, lp);
            Ah[(r16 + 16 * i) * AP + kp] = hp;
            Al[(r16 + 16 * i) * AP + kp] = lp;
        }
        if constexpr (BT) {
            #pragma unroll
            for (int i = 0; i < 4; i++) {
                unsigned int hp, lp;
                cvt_pair(bsv[2 * i], bsv[2 * i + 1], hp, lp);
                Bh[(r16 + 16 * i) * AP + kp] = hp;
                Bl[(r16 + 16 * i) * AP + kp] = lp;
            }
        } else {
            #pragma unroll
            for (int i = 0; i < 8; i++)
                Bp[(kr + 4 * i) * BP_NN + nn] = cvt_one_pack(bsv[i]);
        }
    };

    f32x4 acc[MT];
    #pragma unroll
    for (int i = 0; i < MT; i++) acc[i] = (f32x4){0.f, 0.f, 0.f, 0.f};

    auto computeTile = [&]() {
        f16x8 fbh, fbl;
        if constexpr (BT) {
            int row = w * 16 + fr;
            fbh = __builtin_bit_cast(f16x8, *(const u32x4*)&Bh[row * AP + g * 4]);
            fbl = __builtin_bit_cast(f16x8, *(const u32x4*)&Bl[row * AP + g * 4]);
        } else {
            unsigned int p[8];
            #pragma unroll
            for (int j = 0; j < 8; j++)
                p[j] = Bp[(g * 8 + j) * BP_NN + w * 16 + fr];
            unsigned int hu[4], lu[4];
            #pragma unroll
            for (int r = 0; r < 4; r++) {
                hu[r] = __builtin_amdgcn_perm(p[2 * r + 1], p[2 * r], 0x07060302u);
                lu[r] = __builtin_amdgcn_perm(p[2 * r + 1], p[2 * r], 0x05040100u);
            }
            fbh = __builtin_bit_cast(f16x8, (u32x4){hu[0], hu[1], hu[2], hu[3]});
            fbl = __builtin_bit_cast(f16x8, (u32x4){lu[0], lu[1], lu[2], lu[3]});
        }
        #pragma unroll
        for (int mt = 0; mt < MT; mt++) {
            int row = fr + 16 * mt;
            f16x8 fah = __builtin_bit_cast(f16x8, *(const u32x4*)&Ah[row * AP + g * 4]);
            f16x8 fal = __builtin_bit_cast(f16x8, *(const u32x4*)&Al[row * AP + g * 4]);
            acc[mt] = __builtin_amdgcn_mfma_f32_16x16x32_f16(fah, fbh, acc[mt], 0, 0, 0);
            acc[mt] = __builtin_amdgcn_mfma_f32_16x16x32_f16(fal, fbh, acc[mt], 0, 0, 0);
            acc[mt] = __builtin_amdgcn_mfma_f32_16x16x32_f16(fah, fbl, acc[mt], 0, 0, 0);
        }
    };

    // ---- pipelined main loop ----
    stageA(0); stageB(0);
    storeStage();
    __syncthreads();
    const int nt = Kdim >> 5;
    for (int tt = 0; tt < nt; tt++) {
        const bool more = (tt + 1 < nt);
        if (more) { stageA((tt + 1) * 32); stageB((tt + 1) * 32); }
        computeTile();
        if (more) {
            __syncthreads();
            storeStage();
            __syncthreads();
        }
    }

    // ---- epilogue ----
    const int col = n0 + w * 16 + fr;
    if constexpr (EPI == 0) {
        float* Cb = C + (long)b * sC;
        #pragma unroll
        for (int mt = 0; mt < MT; mt++)
            #pragma unroll
            for (int r = 0; r < 4; r++)
                Cb[(long)(m0 + mt * 16 + g * 4 + r) * Ndim + col] = acc[mt][r];
    } else if constexpr (EPI == 1) {
        #pragma unroll
        for (int mt = 0; mt < MT; mt++)
            #pragma unroll
            for (int r = 0; r < 4; r++) {
                int gr = m0 + mt * 16 + g * 4 + r;
                int sr = (gr >> 5) * 64 + 32 + (gr & 31);
                C[(long)sr * Ndim + col] = acc[mt][r];
            }
    } else if constexpr (EPI == 2) {
        float* Cb = C + (long)b * sC;
        float s = 0.f;
        #pragma unroll
        for (int mt = 0; mt < 2; mt++)
            #pragma unroll
            for (int r = 0; r < 4; r++) {
                int row = mt * 16 + g * 4 + r;
                Cb[(long)row * Ndim + col] = acc[mt][r];
                s += wsh[row] * tanhf(acc[mt][r] + acc[mt + 2][r]);
            }
        s += __shfl_xor(s, 16, 64);
        s += __shfl_xor(s, 32, 64);
        if (g == 0) Yout[(long)b * Ndim + col] = s;
    } else {  // EPI == 3
        const float* Xb = Xadd + (long)b * sC;
        float s = 0.f;
        #pragma unroll
        for (int mt = 0; mt < MT; mt++)
            #pragma unroll
            for (int r = 0; r < 4; r++) {
                int row = mt * 16 + g * 4 + r;
                s += wsh[row] * tanhf(Xb[(long)row * Ndim + col] + acc[mt][r]);
            }
        s += __shfl_xor(s, 16, 64);
        s += __shfl_xor(s, 32, 64);
        if (g == 0) Yout[(long)b * Ndim + col] = s;
    }
}

// ---------------------------------------------------------------------------
// Sa rows 0-31 per batch: rows 0-29 = W_v, 30-31 = 0 (rows 32-63 written by
// the SAMAP GEMM epilogue).
// ---------------------------------------------------------------------------
__global__ void prep_sa_kernel(const float* __restrict__ Wv,
                               float* __restrict__ Sa)
{
    const int b = blockIdx.x, t = threadIdx.x;
    for (int idx = t; idx < 32 * Dn; idx += 256) {
        int row = idx >> 9, col = idx & 511;
        Sa[((long)b * 64 + row) * Dn + col] =
            (row < Kn) ? Wv[(long)row * Dn + col] : 0.f;
    }
}

// ---------------------------------------------------------------------------
// fused softmax(sv[b,:]) + poolv: v1[b,e] = Sum_m a_v[b,m] * V[b,e,m]
// grid (4, Bn) x 1024 thr; each block redoes the (cheap) softmax, pools 128 e.
// ---------------------------------------------------------------------------
__global__ __launch_bounds__(1024) void smpool_v_kernel(
    const float* __restrict__ sv, const float* __restrict__ V,
    float* __restrict__ v1)
{
    const int b = blockIdx.y, qtr = blockIdx.x, t = threadIdx.x;
    const int wid = t >> 6, lane = t & 63;
    __shared__ float red[16];
    __shared__ float bc;
    __shared__ float av[Mn];

    float x = sv[(long)b * Mn + t];
    float v = x;
    #pragma unroll
    for (int off = 32; off > 0; off >>= 1) v = fmaxf(v, __shfl_down(v, off, 64));
    if (lane == 0) red[wid] = v;
    __syncthreads();
    if (t == 0) {
        float m = red[0];
        for (int i = 1; i < 16; i++) m = fmaxf(m, red[i]);
        bc = m;
    }
    __syncthreads();
    float e = expf(x - bc);
    v = e;
    #pragma unroll
    for (int off = 32; off > 0; off >>= 1) v += __shfl_down(v, off, 64);
    if (lane == 0) red[wid] = v;
    __syncthreads();
    if (t == 0) {
        float s = 0.f;
        for (int i = 0; i < 16; i++) s += red[i];
        bc = s;
    }
    __syncthreads();
    av[t] = e / bc;
    __syncthreads();

    f32x4 aa[4];
    #pragma unroll
    for (int i = 0; i < 4; i++) aa[i] = *(const f32x4*)&av[4 * (lane + 64 * i)];

    #pragma unroll
    for (int j = 0; j < 8; j++) {
        int e_ = qtr * 128 + wid * 8 + j;
        const float* vr = V + ((long)b * Dn + e_) * Mn;
        float acc = 0.f;
        #pragma unroll
        for (int i = 0; i < 4; i++) {
            f32x4 vv = *(const f32x4*)&vr[4 * (lane + 64 * i)];
            acc += vv.x * aa[i].x + vv.y * aa[i].y + vv.z * aa[i].z + vv.w * aa[i].w;
        }
        #pragma unroll
        for (int off = 32; off > 0; off >>= 1) acc += __shfl_down(acc, off, 64);
        if (lane == 0) v1[(long)b * Dn + e_] = acc;
    }
}

// ---------------------------------------------------------------------------
// fused softmax(sq[b,:]) + poolq: q1[b,e] = Sum_l a_q[b,l] * Q[b,l,e]
// grid (2, Bn) x 256 thr.
// ---------------------------------------------------------------------------
__global__ __launch_bounds__(256) void smpool_q_kernel(
    const float* __restrict__ sq, const float* __restrict__ Q,
    float* __restrict__ q1)
{
    const int b = blockIdx.y, half = blockIdx.x, t = threadIdx.x;
    const int wid = t >> 6, lane = t & 63;
    __shared__ float red[4];
    __shared__ float bc;
    __shared__ float aq[Ln];

    float x = sq[(long)b * Ln + t];
    float v = x;
    #pragma unroll
    for (int off = 32; off > 0; off >>= 1) v = fmaxf(v, __shfl_down(v, off, 64));
    if (lane == 0) red[wid] = v;
    __syncthreads();
    if (t == 0) {
        float m = red[0];
        for (int i = 1; i < 4; i++) m = fmaxf(m, red[i]);
        bc = m;
    }
    __syncthreads();
    float e = expf(x - bc);
    v = e;
    #pragma unroll
    for (int off = 32; off > 0; off >>= 1) v += __shfl_down(v, off, 64);
    if (lane == 0) red[wid] = v;
    __syncthreads();
    if (t == 0) {
        float s = 0.f;
        for (int i = 0; i < 4; i++) s += red[i];
        bc = s;
    }
    __syncthreads();
    aq[t] = e / bc;
    __syncthreads();

    const int e_ = half * 256 + t;
    const float* Qb = Q + (long)b * Ln * Dn;
    float acc = 0.f;
    #pragma unroll 4
    for (int l = 0; l < Ln; l++)
        acc += aq[l] * Qb[(long)l * Dn + e_];
    q1[(long)b * Dn + e_] = acc;
}

// ---------------------------------------------------------------------------
// Broadcast outputs
// ---------------------------------------------------------------------------
__global__ void bcast_kernel(const float* __restrict__ v1,
                             const float* __restrict__ q1,
                             float* __restrict__ out)
{
    const long nv4 = (long)Bn * Mn * Dn / 4;
    const long nq4 = (long)Bn * Ln * Dn / 4;
    long idx = (long)blockIdx.x * blockDim.x + threadIdx.x;
    float4* o4 = (float4*)out;
    if (idx < nv4) {
        long fidx = idx * 4;
        int e4 = (int)(fidx & (Dn - 1));
        long bm = fidx >> 9;
        int b = (int)(bm >> 10);
        o4[idx] = *(const float4*)(v1 + (long)b * Dn + e4);
    } else if (idx < nv4 + nq4) {
        long fidx = (idx - nv4) * 4;
        int e4 = (int)(fidx & (Dn - 1));
        long bl = fidx >> 9;
        int b = (int)(bl >> 8);
        o4[idx] = *(const float4*)(q1 + (long)b * Dn + e4);
    }
}

// ---------------------------------------------------------------------------

extern "C" void kernel_launch(void* const* d_in, const int* in_sizes, int n_in,
                              void* d_out, int out_size, void* d_ws, size_t ws_size,
                              hipStream_t stream)
{
    const float* V    = (const float*)d_in[0];  // [B, d, M]
    const float* Q    = (const float*)d_in[1];  // [B, L, d]
    const float* W_b  = (const float*)d_in[2];  // [d, d]
    const float* W_v  = (const float*)d_in[3];  // [K, d]
    const float* W_q  = (const float*)d_in[4];  // [K, d]
    const float* w_hv = (const float*)d_in[5];  // [K, 1]
    const float* w_hq = (const float*)d_in[6];  // [K, 1]
    float* out = (float*)d_out;

    // sizes (floats)
    const long szWqQ = (long)Bn * KP * Ln;   // 524288
    const long szU   = (long)Bn * KP * Dn;   // 1048576
    const long szSa  = (long)Bn * 64 * Dn;   // 2097152
    const long szSo  = (long)Bn * 32 * Mn;   // 2097152 (rows 0-31 only)

    float* ws   = (float*)d_ws;
    float* WqQ  = ws;                      // szWqQ
    float* U    = WqQ + szWqQ;             // szU
    float* Sa   = U   + szU;               // szSa
    float* Sout = Sa  + szSa;              // szSo
    float* R    = Sout + szSo;             // szU
    float* G    = R   + szU;               // szU
    float* sv   = G   + szU;               // Bn*Mn
    float* sq   = sv  + (long)Bn * Mn;     // Bn*Ln
    float* v1   = sq  + (long)Bn * Ln;     // Bn*Dn
    float* q1   = v1  + (long)Bn * Dn;     // Bn*Dn

    // 0. Sa rows 0-31 (W_v + zero pad), per batch
    prep_sa_kernel<<<Bn, 256, 0, stream>>>(W_v, Sa);

    // 1. WqQ[b,k,l] = Wq @ Q[b]^T : NT, M=30, N=256, K=512
    fgemm_kernel<2, true, 0><<<dim3(Ln / 64, 1, Bn), 256, 0, stream>>>(
        W_q, Q, WqQ, nullptr, nullptr, nullptr,
        Kn, Ln, Dn, Dn, Dn, 0, (long)Ln * Dn, (long)KP * Ln);

    // 2. U[b] = WqQ[b] @ Q[b] : NN, M=32, N=512, K=256
    fgemm_kernel<2, false, 0><<<dim3(Dn / 64, 1, Bn), 256, 0, stream>>>(
        WqQ, Q, U, nullptr, nullptr, nullptr,
        KP, Dn, Ln, Ln, Dn, (long)KP * Ln, (long)Ln * Dn, (long)KP * Dn);

    // 3. P = Uflat[2048,512] @ W_b : NN, written directly into Sa rows 32-63
    fgemm_kernel<4, false, 1><<<dim3(Dn / 64, Bn * KP / 64, 1), 256, 0, stream>>>(
        U, W_b, Sa, nullptr, nullptr, nullptr,
        Bn * KP, Dn, Dn, Dn, Dn, 0, 0, 0);

    // 5. Sout[b](rows 0-31) = (Sa[b] @ V[b]) rows 0-31 : NN, M=64, N=1024,
    //    K=512; sv fused in epilogue (rows 32-63 consumed in-register).
    fgemm_kernel<4, false, 2><<<dim3(Mn / 64, 1, Bn), 256, 0, stream>>>(
        Sa, V, Sout, w_hv, nullptr, sv,
        64, Mn, Dn, Dn, Mn, (long)64 * Dn, (long)Dn * Mn, (long)32 * Mn);

    // 7. R[b,k,e] = Sum_m Sout[k,m] V[e,m] : NT, M=32, N=512, K=1024
    fgemm_kernel<2, true, 0><<<dim3(Dn / 64, 1, Bn), 256, 0, stream>>>(
        Sout, V, R, nullptr, nullptr, nullptr,
        KP, Dn, Mn, Mn, Mn, (long)32 * Mn, (long)Dn * Mn, (long)KP * Dn);

    // 8. G = Rflat[2048,512] @ W_b^T : NT
    fgemm_kernel<4, true, 0><<<dim3(Dn / 64, Bn * KP / 64, 1), 256, 0, stream>>>(
        R, W_b, G, nullptr, nullptr, nullptr,
        Bn * KP, Dn, Dn, Dn, Dn, 0, 0, 0);

    // 9. Tq = G @ Q^T : NT, M=32, N=256, K=512; sq fused (Tq never stored)
    fgemm_kernel<2, true, 3><<<dim3(Ln / 64, 1, Bn), 256, 0, stream>>>(
        G, Q, nullptr, w_hq, WqQ, sq,
        KP, Ln, Dn, Dn, Dn, (long)KP * Dn, (long)Ln * Dn, (long)KP * Ln);

    // 11+12a. softmax(sv) + poolv fused
    smpool_v_kernel<<<dim3(4, Bn), 1024, 0, stream>>>(sv, V, v1);

    // 11+12b. softmax(sq) + poolq fused
    smpool_q_kernel<<<dim3(2, Bn), 256, 0, stream>>>(sq, Q, q1);

    // 13. broadcast outputs
    {
        long n4 = (long)Bn * Mn * Dn / 4 + (long)Bn * Ln * Dn / 4;
        bcast_kernel<<<(int)((n4 + 255) / 256), 256, 0, stream>>>(v1, q1, out);
    }
}

// Round 4
// 457.177 us; speedup vs baseline: 1.4388x; 1.0818x over previous
//
#include <hip/hip_runtime.h>

// Problem dims
constexpr int Bn = 64;     // batch
constexpr int Dn = 512;    // embed dim
constexpr int Mn = 1024;   // M
constexpr int Ln = 256;    // L
constexpr int Kn = 30;     // K heads
constexpr int KP = 32;     // K padded to 32 rows

typedef __attribute__((ext_vector_type(4))) float f32x4;
typedef __attribute__((ext_vector_type(2))) float f32x2;
typedef __attribute__((ext_vector_type(4))) unsigned int u32x4;
typedef __attribute__((ext_vector_type(8))) _Float16 f16x8;
typedef __attribute__((ext_vector_type(2))) _Float16 f16x2;
typedef unsigned short ushort_t;

// ---------------------------------------------------------------------------
// fp32 -> fp16 hi/lo split (x = hi + lo, each fp16; ~22 effective mantissa
// bits). All intermediates are well inside fp16 normal range (max ~4e3).
// ---------------------------------------------------------------------------
__device__ __forceinline__ void cvt_pair(float a, float b,
                                         unsigned int& hp, unsigned int& lp)
{
    _Float16 ha = (_Float16)a, hb = (_Float16)b;
    _Float16 la = (_Float16)(a - (float)ha), lb = (_Float16)(b - (float)hb);
    f16x2 hv = {ha, hb}, lv = {la, lb};
    hp = __builtin_bit_cast(unsigned int, hv);
    lp = __builtin_bit_cast(unsigned int, lv);
}

__device__ __forceinline__ unsigned int cvt_one_pack(float x)
{
    _Float16 h = (_Float16)x;
    _Float16 l = (_Float16)(x - (float)h);
    return (unsigned int)__builtin_bit_cast(ushort_t, l) |
           ((unsigned int)__builtin_bit_cast(ushort_t, h) << 16);
}

// ---------------------------------------------------------------------------
// Unified split-fp16 MFMA GEMM, 2-stage software pipelined, split-K capable.
//   C[ks][b][M][N] = (A) @ (B)  with
//     NN (BT=false): B[b] is [K][N] row-major, row stride ldB
//     NT (BT=true):  B[b] is [N][K] row-major, row stride ldB
//   A[b] is [M][K] row-major, row stride ldA. Rows >= Mreal read as 0.
//   BM = MT*16, BN = 64, BK = 32. 256 threads = 4 waves; wave w owns cols
//   [w*16, w*16+16). grid: (Ndim/64, mblocks*KS, batches).
//   KS: K split into KS chunks; chunk ks writes C slab at ks*slabC.
//   ASRC: 0 = plain A; 1 = A is a 2-slab producer output: read
//         Ab[off] + Ab[sASlab+off] (consumer-side slab reduction);
//         2 = concat: rows<30 from A (=W_v, no batch), 30-31 zero, rows>=32
//         from A2[(b*32+row-32)*ldA] summed over 2 slabs (stride sASlab).
//   EPI: 0 = plain C write (to slab ks)
//        2 = SV : write rows<32 of C; sv[b,col] = sum_k w[k]*tanh(acc_k +
//                 acc_{k+32}) via shfl reduce  (requires MT=4, KS=1)
//        3 = SQ : no C write; sq[b,col] = sum_k w[k]*tanh(X[k,col]+acc_k),
//                 X read 2-slab-summed if XSUM (requires MT=2, KS=1;
//                 sC = X batch stride)
// ---------------------------------------------------------------------------
template <int MT, bool BT, int EPI, int KS, int ASRC, bool XSUM>
__global__ __launch_bounds__(256) void fgemm_kernel(
    const float* __restrict__ A, const float* __restrict__ B,
    const float* __restrict__ A2,
    float* __restrict__ C,
    const float* __restrict__ Wvec, const float* __restrict__ Xadd,
    float* __restrict__ Yout,
    int Mreal, int Ndim, int Kdim, int ldA, int ldB,
    long sA, long sB, long sC,
    long sASlab, long slabC, long sXslab)
{
    constexpr int BM = MT * 16;
    constexpr int AP = 20;                      // u32 pitch: 16 data + 4 pad
    constexpr int ASZ = BM * AP;                // one A plane
    constexpr int BP_NN = 66;                   // NN packed pitch (64 + 2 pad)
    constexpr int BSZ = BT ? (2 * 64 * AP) : (32 * BP_NN);
    __shared__ unsigned int smem[2 * ASZ + BSZ];
    __shared__ float wsh[32];
    unsigned int* Ah = smem;
    unsigned int* Al = smem + ASZ;
    unsigned int* Bh = smem + 2 * ASZ;          // BT planes
    unsigned int* Bl = Bh + 64 * AP;
    unsigned int* Bp = smem + 2 * ASZ;          // NN packed lo|hi

    const int t  = threadIdx.x;
    const int n0 = blockIdx.x * 64;
    const int mb = blockIdx.y / KS, ks = blockIdx.y % KS;
    const int m0 = mb * BM;
    const int b  = blockIdx.z;
    const float* Ab = A + (long)b * sA;
    const float* Bb = B + (long)b * sB;

    const int lane = t & 63, w = t >> 6;
    const int fr = lane & 15, g = lane >> 4;
    const int kp  = t & 15, r16 = t >> 4;       // 16 threads per row staging
    const int nn  = t & 63, kr  = t >> 6;       // NN B staging

    const int kLen = Kdim / KS;
    const int k00  = ks * kLen;
    const int nt   = kLen >> 5;

    if (EPI >= 2 && t < 32) wsh[t] = (t < Kn) ? Wvec[t] : 0.f;

    float as[MT][2];
    float bsv[8];

    auto stageA = [&](int k0) {
        #pragma unroll
        for (int i = 0; i < MT; i++) {
            int gm = m0 + r16 + 16 * i;
            float x0 = 0.f, x1 = 0.f;
            if constexpr (ASRC == 2) {
                if (gm < Kn) {
                    f32x2 v = *(const f32x2*)&A[(long)gm * ldA + k0 + 2 * kp];
                    x0 = v.x; x1 = v.y;
                } else if (gm >= 32) {
                    const float* p = &A2[((long)b * 32 + gm - 32) * ldA + k0 + 2 * kp];
                    f32x2 v  = *(const f32x2*)p;
                    f32x2 v2 = *(const f32x2*)(p + sASlab);
                    x0 = v.x + v2.x; x1 = v.y + v2.y;
                }
            } else if constexpr (ASRC == 1) {
                if (gm < Mreal) {
                    const float* p = &Ab[(long)gm * ldA + k0 + 2 * kp];
                    f32x2 v  = *(const f32x2*)p;
                    f32x2 v2 = *(const f32x2*)(p + sASlab);
                    x0 = v.x + v2.x; x1 = v.y + v2.y;
                }
            } else {
                if (gm < Mreal) {
                    f32x2 v = *(const f32x2*)&Ab[(long)gm * ldA + k0 + 2 * kp];
                    x0 = v.x; x1 = v.y;
                }
            }
            as[i][0] = x0; as[i][1] = x1;
        }
    };
    auto stageB = [&](int k0) {
        if constexpr (BT) {
            #pragma unroll
            for (int i = 0; i < 4; i++) {
                f32x2 v = *(const f32x2*)&Bb[(long)(n0 + r16 + 16 * i) * ldB + k0 + 2 * kp];
                bsv[2 * i] = v.x; bsv[2 * i + 1] = v.y;
            }
        } else {
            #pragma unroll
            for (int i = 0; i < 8; i++)
                bsv[i] = Bb[(long)(k0 + kr + 4 * i) * ldB + n0 + nn];
        }
    };
    auto storeStage = [&]() {
        #pragma unroll
        for (int i = 0; i < MT; i++) {
            unsigned int hp, lp;
            cvt_pair(as[i][0], as[i][1], hp, lp);
            Ah[(r16 + 16 * i) * AP + kp] = hp;
            Al[(r16 + 16 * i) * AP + kp] = lp;
        }
        if constexpr (BT) {
            #pragma unroll
            for (int i = 0; i < 4; i++) {
                unsigned int hp, lp;
                cvt_pair(bsv[2 * i], bsv[2 * i + 1], hp, lp);
                Bh[(r16 + 16 * i) * AP + kp] = hp;
                Bl[(r16 + 16 * i) * AP + kp] = lp;
            }
        } else {
            #pragma unroll
            for (int i = 0; i < 8; i++)
                Bp[(kr + 4 * i) * BP_NN + nn] = cvt_one_pack(bsv[i]);
        }
    };

    f32x4 acc[MT];
    #pragma unroll
    for (int i = 0; i < MT; i++) acc[i] = (f32x4){0.f, 0.f, 0.f, 0.f};

    auto computeTile = [&]() {
        f16x8 fbh, fbl;
        if constexpr (BT) {
            int row = w * 16 + fr;
            fbh = __builtin_bit_cast(f16x8, *(const u32x4*)&Bh[row * AP + g * 4]);
            fbl = __builtin_bit_cast(f16x8, *(const u32x4*)&Bl[row * AP + g * 4]);
        } else {
            unsigned int p[8];
            #pragma unroll
            for (int j = 0; j < 8; j++)
                p[j] = Bp[(g * 8 + j) * BP_NN + w * 16 + fr];
            unsigned int hu[4], lu[4];
            #pragma unroll
            for (int r = 0; r < 4; r++) {
                hu[r] = __builtin_amdgcn_perm(p[2 * r + 1], p[2 * r], 0x07060302u);
                lu[r] = __builtin_amdgcn_perm(p[2 * r + 1], p[2 * r], 0x05040100u);
            }
            fbh = __builtin_bit_cast(f16x8, (u32x4){hu[0], hu[1], hu[2], hu[3]});
            fbl = __builtin_bit_cast(f16x8, (u32x4){lu[0], lu[1], lu[2], lu[3]});
        }
        #pragma unroll
        for (int mt = 0; mt < MT; mt++) {
            int row = fr + 16 * mt;
            f16x8 fah = __builtin_bit_cast(f16x8, *(const u32x4*)&Ah[row * AP + g * 4]);
            f16x8 fal = __builtin_bit_cast(f16x8, *(const u32x4*)&Al[row * AP + g * 4]);
            acc[mt] = __builtin_amdgcn_mfma_f32_16x16x32_f16(fah, fbh, acc[mt], 0, 0, 0);
            acc[mt] = __builtin_amdgcn_mfma_f32_16x16x32_f16(fal, fbh, acc[mt], 0, 0, 0);
            acc[mt] = __builtin_amdgcn_mfma_f32_16x16x32_f16(fah, fbl, acc[mt], 0, 0, 0);
        }
    };

    // ---- pipelined main loop ----
    stageA(k00); stageB(k00);
    storeStage();
    __syncthreads();
    for (int tt = 0; tt < nt; tt++) {
        const bool more = (tt + 1 < nt);
        if (more) { stageA(k00 + (tt + 1) * 32); stageB(k00 + (tt + 1) * 32); }
        computeTile();
        if (more) {
            __syncthreads();
            storeStage();
            __syncthreads();
        }
    }

    // ---- epilogue ----
    const int col = n0 + w * 16 + fr;
    if constexpr (EPI == 0) {
        float* Cb = C + (long)ks * slabC + (long)b * sC;
        #pragma unroll
        for (int mt = 0; mt < MT; mt++)
            #pragma unroll
            for (int r = 0; r < 4; r++)
                Cb[(long)(m0 + mt * 16 + g * 4 + r) * Ndim + col] = acc[mt][r];
    } else if constexpr (EPI == 2) {
        float* Cb = C + (long)b * sC;
        float s = 0.f;
        #pragma unroll
        for (int mt = 0; mt < 2; mt++)
            #pragma unroll
            for (int r = 0; r < 4; r++) {
                int row = mt * 16 + g * 4 + r;
                Cb[(long)row * Ndim + col] = acc[mt][r];
                s += wsh[row] * tanhf(acc[mt][r] + acc[mt + 2][r]);
            }
        s += __shfl_xor(s, 16, 64);
        s += __shfl_xor(s, 32, 64);
        if (g == 0) Yout[(long)b * Ndim + col] = s;
    } else {  // EPI == 3
        const float* Xb = Xadd + (long)b * sC;
        float s = 0.f;
        #pragma unroll
        for (int mt = 0; mt < MT; mt++)
            #pragma unroll
            for (int r = 0; r < 4; r++) {
                int row = mt * 16 + g * 4 + r;
                float x = Xb[(long)row * Ndim + col];
                if constexpr (XSUM) x += Xb[sXslab + (long)row * Ndim + col];
                s += wsh[row] * tanhf(x + acc[mt][r]);
            }
        s += __shfl_xor(s, 16, 64);
        s += __shfl_xor(s, 32, 64);
        if (g == 0) Yout[(long)b * Ndim + col] = s;
    }
}

// ---------------------------------------------------------------------------
// fused softmax(sv[b,:]) + poolv: v1[b,e] = Sum_m a_v[b,m] * V[b,e,m]
// grid (4, Bn) x 1024 thr; each block redoes the (cheap) softmax, pools 128 e.
// ---------------------------------------------------------------------------
__global__ __launch_bounds__(1024) void smpool_v_kernel(
    const float* __restrict__ sv, const float* __restrict__ V,
    float* __restrict__ v1)
{
    const int b = blockIdx.y, qtr = blockIdx.x, t = threadIdx.x;
    const int wid = t >> 6, lane = t & 63;
    __shared__ float red[16];
    __shared__ float bc;
    __shared__ float av[Mn];

    float x = sv[(long)b * Mn + t];
    float v = x;
    #pragma unroll
    for (int off = 32; off > 0; off >>= 1) v = fmaxf(v, __shfl_down(v, off, 64));
    if (lane == 0) red[wid] = v;
    __syncthreads();
    if (t == 0) {
        float m = red[0];
        for (int i = 1; i < 16; i++) m = fmaxf(m, red[i]);
        bc = m;
    }
    __syncthreads();
    float e = expf(x - bc);
    v = e;
    #pragma unroll
    for (int off = 32; off > 0; off >>= 1) v += __shfl_down(v, off, 64);
    if (lane == 0) red[wid] = v;
    __syncthreads();
    if (t == 0) {
        float s = 0.f;
        for (int i = 0; i < 16; i++) s += red[i];
        bc = s;
    }
    __syncthreads();
    av[t] = e / bc;
    __syncthreads();

    f32x4 aa[4];
    #pragma unroll
    for (int i = 0; i < 4; i++) aa[i] = *(const f32x4*)&av[4 * (lane + 64 * i)];

    #pragma unroll
    for (int j = 0; j < 8; j++) {
        int e_ = qtr * 128 + wid * 8 + j;
        const float* vr = V + ((long)b * Dn + e_) * Mn;
        float acc = 0.f;
        #pragma unroll
        for (int i = 0; i < 4; i++) {
            f32x4 vv = *(const f32x4*)&vr[4 * (lane + 64 * i)];
            acc += vv.x * aa[i].x + vv.y * aa[i].y + vv.z * aa[i].z + vv.w * aa[i].w;
        }
        #pragma unroll
        for (int off = 32; off > 0; off >>= 1) acc += __shfl_down(acc, off, 64);
        if (lane == 0) v1[(long)b * Dn + e_] = acc;
    }
}

// ---------------------------------------------------------------------------
// fused softmax(sq[b,:]) + poolq: q1[b,e] = Sum_l a_q[b,l] * Q[b,l,e]
// grid (Dn/64=8, Bn) x 256 thr; 4 threads per output e (l split in 4).
// ---------------------------------------------------------------------------
__global__ __launch_bounds__(256) void smpool_q_kernel(
    const float* __restrict__ sq, const float* __restrict__ Q,
    float* __restrict__ q1)
{
    const int b = blockIdx.y, eb = blockIdx.x, t = threadIdx.x;
    const int wid = t >> 6, lane = t & 63;
    __shared__ float red[4];
    __shared__ float bc;
    __shared__ float aq[Ln];

    float x = sq[(long)b * Ln + t];
    float v = x;
    #pragma unroll
    for (int off = 32; off > 0; off >>= 1) v = fmaxf(v, __shfl_down(v, off, 64));
    if (lane == 0) red[wid] = v;
    __syncthreads();
    if (t == 0) {
        float m = red[0];
        for (int i = 1; i < 4; i++) m = fmaxf(m, red[i]);
        bc = m;
    }
    __syncthreads();
    float e = expf(x - bc);
    v = e;
    #pragma unroll
    for (int off = 32; off > 0; off >>= 1) v += __shfl_down(v, off, 64);
    if (lane == 0) red[wid] = v;
    __syncthreads();
    if (t == 0) {
        float s = 0.f;
        for (int i = 0; i < 4; i++) s += red[i];
        bc = s;
    }
    __syncthreads();
    aq[t] = e / bc;
    __syncthreads();

    const int e_ = eb * 64 + (t >> 2), qtr = t & 3;
    const float* Qb = Q + (long)b * Ln * Dn;
    float acc = 0.f;
    #pragma unroll 4
    for (int i = 0; i < 64; i++) {
        int l = qtr * 64 + i;
        acc += aq[l] * Qb[(long)l * Dn + e_];
    }
    acc += __shfl_xor(acc, 1, 64);
    acc += __shfl_xor(acc, 2, 64);
    if (qtr == 0) q1[(long)b * Dn + e_] = acc;
}

// ---------------------------------------------------------------------------
// Broadcast outputs
// ---------------------------------------------------------------------------
__global__ void bcast_kernel(const float* __restrict__ v1,
                             const float* __restrict__ q1,
                             float* __restrict__ out)
{
    const long nv4 = (long)Bn * Mn * Dn / 4;
    const long nq4 = (long)Bn * Ln * Dn / 4;
    long idx = (long)blockIdx.x * blockDim.x + threadIdx.x;
    float4* o4 = (float4*)out;
    if (idx < nv4) {
        long fidx = idx * 4;
        int e4 = (int)(fidx & (Dn - 1));
        long bm = fidx >> 9;
        int b = (int)(bm >> 10);
        o4[idx] = *(const float4*)(v1 + (long)b * Dn + e4);
    } else if (idx < nv4 + nq4) {
        long fidx = (idx - nv4) * 4;
        int e4 = (int)(fidx & (Dn - 1));
        long bl = fidx >> 9;
        int b = (int)(bl >> 8);
        o4[idx] = *(const float4*)(q1 + (long)b * Dn + e4);
    }
}

// ---------------------------------------------------------------------------

extern "C" void kernel_launch(void* const* d_in, const int* in_sizes, int n_in,
                              void* d_out, int out_size, void* d_ws, size_t ws_size,
                              hipStream_t stream)
{
    const float* V    = (const float*)d_in[0];  // [B, d, M]
    const float* Q    = (const float*)d_in[1];  // [B, L, d]
    const float* W_b  = (const float*)d_in[2];  // [d, d]
    const float* W_v  = (const float*)d_in[3];  // [K, d]
    const float* W_q  = (const float*)d_in[4];  // [K, d]
    const float* w_hv = (const float*)d_in[5];  // [K, 1]
    const float* w_hq = (const float*)d_in[6];  // [K, 1]
    float* out = (float*)d_out;

    // sizes (floats)
    const long szWqQ = (long)Bn * KP * Ln;   // 524288
    const long szU   = (long)Bn * KP * Dn;   // 1048576
    const long szSo  = (long)Bn * 32 * Mn;   // 2097152

    float* ws   = (float*)d_ws;
    float* WqQ2 = ws;                       // 2 slabs: 2*szWqQ
    float* U2   = WqQ2 + 2 * szWqQ;         // 2*szU
    float* P2   = U2   + 2 * szU;           // 2*szU
    float* Sout = P2   + 2 * szU;           // szSo
    float* R2   = Sout + szSo;              // 2*szU
    float* G2   = R2   + 2 * szU;           // 2*szU
    float* sv   = G2   + 2 * szU;           // Bn*Mn
    float* sq   = sv   + (long)Bn * Mn;     // Bn*Ln
    float* v1   = sq   + (long)Bn * Ln;     // Bn*Dn
    float* q1   = v1   + (long)Bn * Dn;     // Bn*Dn

    // g1. WqQ[b,k,l] = Wq @ Q[b]^T : NT, M=30, N=256, K=512, KS=2 (512 blk)
    fgemm_kernel<2, true, 0, 2, 0, false><<<dim3(4, 2, 64), 256, 0, stream>>>(
        W_q, Q, nullptr, WqQ2, nullptr, nullptr, nullptr,
        Kn, Ln, Dn, Dn, Dn,
        0, (long)Ln * Dn, (long)KP * Ln,
        0, szWqQ, 0);

    // g2. U[b] = WqQ[b] @ Q[b] : NN, M=32, N=512, K=256, KS=2, A=slab-sum
    fgemm_kernel<2, false, 0, 2, 1, false><<<dim3(8, 2, 64), 256, 0, stream>>>(
        WqQ2, Q, nullptr, U2, nullptr, nullptr, nullptr,
        KP, Dn, Ln, Ln, Dn,
        (long)KP * Ln, (long)Ln * Dn, (long)KP * Dn,
        szWqQ, szU, 0);

    // g3. P = Uflat[2048,512] @ W_b : NN, KS=2, A=slab-sum (512 blk)
    fgemm_kernel<4, false, 0, 2, 1, false><<<dim3(8, 64, 1), 256, 0, stream>>>(
        U2, W_b, nullptr, P2, nullptr, nullptr, nullptr,
        Bn * KP, Dn, Dn, Dn, Dn,
        0, 0, 0,
        szU, szU, 0);

    // g5. Sout[b](rows 0-31) = ([W_v;0;P[b]] @ V[b]) : NN, M=64, N=1024,
    //     K=512; A rows from W_v/zero/P-slab-sum (ASRC=2); sv fused (EPI=2).
    fgemm_kernel<4, false, 2, 1, 2, false><<<dim3(16, 1, 64), 256, 0, stream>>>(
        W_v, V, P2, Sout, w_hv, nullptr, sv,
        64, Mn, Dn, Dn, Mn,
        0, (long)Dn * Mn, (long)32 * Mn,
        szU, 0, 0);

    // g7. R[b,k,e] = Sum_m Sout[k,m] V[e,m] : NT, M=32, N=512, K=1024, KS=2
    fgemm_kernel<2, true, 0, 2, 0, false><<<dim3(8, 2, 64), 256, 0, stream>>>(
        Sout, V, nullptr, R2, nullptr, nullptr, nullptr,
        KP, Dn, Mn, Mn, Mn,
        (long)32 * Mn, (long)Dn * Mn, (long)KP * Dn,
        0, szU, 0);

    // g8. G = Rflat[2048,512] @ W_b^T : NT, KS=2, A=slab-sum (512 blk)
    fgemm_kernel<4, true, 0, 2, 1, false><<<dim3(8, 64, 1), 256, 0, stream>>>(
        R2, W_b, nullptr, G2, nullptr, nullptr, nullptr,
        Bn * KP, Dn, Dn, Dn, Dn,
        0, 0, 0,
        szU, szU, 0);

    // g9. Tq = G @ Q^T : NT, M=32, N=256, K=512; A=G-slab-sum; sq fused
    //     (EPI=3) with X = WqQ-slab-sum (XSUM).
    fgemm_kernel<2, true, 3, 1, 1, true><<<dim3(4, 1, 64), 256, 0, stream>>>(
        G2, Q, nullptr, nullptr, w_hq, WqQ2, sq,
        KP, Ln, Dn, Dn, Dn,
        (long)KP * Dn, (long)Ln * Dn, (long)KP * Ln,
        szU, 0, szWqQ);

    // softmax(sv) + poolv fused
    smpool_v_kernel<<<dim3(4, Bn), 1024, 0, stream>>>(sv, V, v1);

    // softmax(sq) + poolq fused
    smpool_q_kernel<<<dim3(8, Bn), 256, 0, stream>>>(sq, Q, q1);

    // broadcast outputs
    {
        long n4 = (long)Bn * Mn * Dn / 4 + (long)Bn * Ln * Dn / 4;
        bcast_kernel<<<(int)((n4 + 255) / 256), 256, 0, stream>>>(v1, q1, out);
    }
}

// Round 5
// 451.837 us; speedup vs baseline: 1.4558x; 1.0118x over previous
//
#include <hip/hip_runtime.h>

// Problem dims
constexpr int Bn = 64;     // batch
constexpr int Dn = 512;    // embed dim
constexpr int Mn = 1024;   // M
constexpr int Ln = 256;    // L
constexpr int Kn = 30;     // K heads
constexpr int KP = 32;     // K padded to 32 rows

typedef __attribute__((ext_vector_type(4))) float f32x4;
typedef __attribute__((ext_vector_type(2))) float f32x2;
typedef __attribute__((ext_vector_type(4))) unsigned int u32x4;
typedef __attribute__((ext_vector_type(2))) unsigned int u32x2;
typedef __attribute__((ext_vector_type(8))) _Float16 f16x8;
typedef __attribute__((ext_vector_type(2))) _Float16 f16x2;
typedef unsigned short ushort_t;

// ---------------------------------------------------------------------------
// split-fp16 packed format: u32 = (hi<<16) | lo, x = hi + lo (~22 mantissa
// bits). All values well inside fp16 normal range (max ~4e3 << 65504).
// ---------------------------------------------------------------------------
__device__ __forceinline__ unsigned int cvt_one_pack(float x)
{
    _Float16 h = (_Float16)x;
    _Float16 l = (_Float16)(x - (float)h);
    return (unsigned int)__builtin_bit_cast(ushort_t, l) |
           ((unsigned int)__builtin_bit_cast(ushort_t, h) << 16);
}

__device__ __forceinline__ float unpacksplit(unsigned int p)
{
    _Float16 h = __builtin_bit_cast(_Float16, (ushort_t)(p >> 16));
    _Float16 l = __builtin_bit_cast(_Float16, (ushort_t)(p & 0xffffu));
    return (float)h + (float)l;
}

__device__ __forceinline__ void cvt_pair(float a, float b,
                                         unsigned int& hp, unsigned int& lp)
{
    _Float16 ha = (_Float16)a, hb = (_Float16)b;
    _Float16 la = (_Float16)(a - (float)ha), lb = (_Float16)(b - (float)hb);
    f16x2 hv = {ha, hb}, lv = {la, lb};
    hp = __builtin_bit_cast(unsigned int, hv);
    lp = __builtin_bit_cast(unsigned int, lv);
}

// perm selectors: from packed pair (p0=(h0<<16)|l0, p1=(h1<<16)|l1)
//   perm(p1, p0, 0x07060302) = (h1<<16)|h0  (f16x2 hi-plane pair)
//   perm(p1, p0, 0x05040100) = (l1<<16)|l0  (f16x2 lo-plane pair)
#define PERM_HI 0x07060302u
#define PERM_LO 0x05040100u

// ---------------------------------------------------------------------------
// one-shot fp32 -> packed split-fp16 for up to 4 arrays (sizes %4 == 0)
// ---------------------------------------------------------------------------
__global__ __launch_bounds__(256) void pack4_kernel(
    const float* __restrict__ s0, unsigned int* __restrict__ d0, long n0,
    const float* __restrict__ s1, unsigned int* __restrict__ d1, long n1,
    const float* __restrict__ s2, unsigned int* __restrict__ d2, long n2,
    const float* __restrict__ s3, unsigned int* __restrict__ d3, long n3)
{
    long total4 = (n0 + n1 + n2 + n3) >> 2;
    long stride = (long)gridDim.x * blockDim.x;
    for (long c = (long)blockIdx.x * blockDim.x + threadIdx.x; c < total4; c += stride) {
        long i = c * 4;
        const float* s; unsigned int* d; long off;
        if (i < n0)                { s = s0; d = d0; off = i; }
        else if (i < n0 + n1)      { s = s1; d = d1; off = i - n0; }
        else if (i < n0 + n1 + n2) { s = s2; d = d2; off = i - n0 - n1; }
        else                       { s = s3; d = d3; off = i - n0 - n1 - n2; }
        f32x4 v = *(const f32x4*)(s + off);
        u32x4 o = { cvt_one_pack(v.x), cvt_one_pack(v.y),
                    cvt_one_pack(v.z), cvt_one_pack(v.w) };
        *(u32x4*)(d + off) = o;
    }
}

// ---------------------------------------------------------------------------
// Split-fp16 MFMA GEMM on packed operands, true LDS double-buffer
// (1 barrier per K-iteration).
//   C[b][M][N] = A @ B ; A always packed split-fp16 (u32/elem).
//     NN (BT=false): B[b] is [K][N] row-major, row stride ldB
//     NT (BT=true):  B[b] is [N][K] row-major, row stride ldB
//   BPACK: B packed (u32) vs fp32 (in-loop convert; used for V only).
//   BM = MT*16, BN = 64, BK = 32, 256 thr = 4 waves, wave w owns cols
//   [w*16,w*16+16). grid (Ndim/64, mblocks, batches).
//   ASRC: 0 = plain A (rows >= Mreal read 0); 2 = concat rows<30 from A
//         (=W_v packed), 30-31 zero, rows>=32 from A2[(b*32+row-32)*ldA].
//   EPI: 0 = packed C write
//        2 = SV: packed C rows<32; sv[b,col] = sum_k w[k]*tanh(acc_k +
//             acc_{k+32}) shfl-reduced (MT=4)
//        3 = SQ: no C; sq[b,col] = sum_k w[k]*tanh(unpack(X)+acc_k) (MT=2,
//             sC = X batch stride)
// ---------------------------------------------------------------------------
template <int MT, bool BT, int EPI, bool BPACK, int ASRC>
__global__ __launch_bounds__(256) void fgemm_kernel(
    const unsigned int* __restrict__ A, const void* __restrict__ B,
    const unsigned int* __restrict__ A2,
    unsigned int* __restrict__ C,
    const float* __restrict__ Wvec, const unsigned int* __restrict__ Xadd,
    float* __restrict__ Yout,
    int Mreal, int Ndim, int Kdim, int ldA, int ldB,
    long sA, long sB, long sC)
{
    constexpr int BM = MT * 16;
    constexpr int AP = 20;                      // u32 pitch: 16 data + 4 pad
    constexpr int ASZ = BM * AP;                // one A plane
    constexpr int BP_NN = 66;                   // NN packed pitch (64 + 2 pad)
    constexpr int BSZ = BT ? (2 * 64 * AP) : (32 * BP_NN);
    constexpr int HALF = 2 * ASZ + BSZ;
    __shared__ unsigned int smem[2 * HALF];
    __shared__ float wsh[32];

    const int t  = threadIdx.x;
    const int n0 = blockIdx.x * 64;
    const int m0 = blockIdx.y * BM;
    const int b  = blockIdx.z;
    const unsigned int* Ab = A + (long)b * sA;
    const float*        Bf = (const float*)B + (long)b * sB;
    const unsigned int* Bu = (const unsigned int*)B + (long)b * sB;

    const int lane = t & 63, w = t >> 6;
    const int fr = lane & 15, g = lane >> 4;
    const int kp  = t & 15, r16 = t >> 4;       // 16 threads per row staging
    const int nn  = t & 63, kr  = t >> 6;       // NN B staging

    if (EPI >= 2 && t < 32) wsh[t] = (t < Kn) ? Wvec[t] : 0.f;

    unsigned int aA[MT][2];
    unsigned int bu[8];
    float bf[8];

    auto stageA = [&](int k0) {
        #pragma unroll
        for (int i = 0; i < MT; i++) {
            int gm = m0 + r16 + 16 * i;
            unsigned int p0 = 0, p1 = 0;
            if constexpr (ASRC == 2) {
                if (gm < Kn) {
                    u32x2 v = *(const u32x2*)&A[(long)gm * ldA + k0 + 2 * kp];
                    p0 = v.x; p1 = v.y;
                } else if (gm >= 32) {
                    u32x2 v = *(const u32x2*)&A2[((long)b * 32 + gm - 32) * ldA + k0 + 2 * kp];
                    p0 = v.x; p1 = v.y;
                }
            } else {
                if (gm < Mreal) {
                    u32x2 v = *(const u32x2*)&Ab[(long)gm * ldA + k0 + 2 * kp];
                    p0 = v.x; p1 = v.y;
                }
            }
            aA[i][0] = p0; aA[i][1] = p1;
        }
    };
    auto stageB = [&](int k0) {
        if constexpr (BT) {
            #pragma unroll
            for (int i = 0; i < 4; i++) {
                long off = (long)(n0 + r16 + 16 * i) * ldB + k0 + 2 * kp;
                if constexpr (BPACK) {
                    u32x2 v = *(const u32x2*)&Bu[off];
                    bu[2 * i] = v.x; bu[2 * i + 1] = v.y;
                } else {
                    f32x2 v = *(const f32x2*)&Bf[off];
                    bf[2 * i] = v.x; bf[2 * i + 1] = v.y;
                }
            }
        } else {
            #pragma unroll
            for (int i = 0; i < 8; i++) {
                long off = (long)(k0 + kr + 4 * i) * ldB + n0 + nn;
                if constexpr (BPACK) bu[i] = Bu[off];
                else                 bf[i] = Bf[off];
            }
        }
    };
    auto storeStage = [&](unsigned int* sm) {
        unsigned int* Ah = sm;
        unsigned int* Al = sm + ASZ;
        #pragma unroll
        for (int i = 0; i < MT; i++) {
            Ah[(r16 + 16 * i) * AP + kp] = __builtin_amdgcn_perm(aA[i][1], aA[i][0], PERM_HI);
            Al[(r16 + 16 * i) * AP + kp] = __builtin_amdgcn_perm(aA[i][1], aA[i][0], PERM_LO);
        }
        if constexpr (BT) {
            unsigned int* Bh = sm + 2 * ASZ;
            unsigned int* Bl = Bh + 64 * AP;
            #pragma unroll
            for (int i = 0; i < 4; i++) {
                unsigned int hp, lp;
                if constexpr (BPACK) {
                    hp = __builtin_amdgcn_perm(bu[2 * i + 1], bu[2 * i], PERM_HI);
                    lp = __builtin_amdgcn_perm(bu[2 * i + 1], bu[2 * i], PERM_LO);
                } else {
                    cvt_pair(bf[2 * i], bf[2 * i + 1], hp, lp);
                }
                Bh[(r16 + 16 * i) * AP + kp] = hp;
                Bl[(r16 + 16 * i) * AP + kp] = lp;
            }
        } else {
            unsigned int* Bp = sm + 2 * ASZ;
            #pragma unroll
            for (int i = 0; i < 8; i++)
                Bp[(kr + 4 * i) * BP_NN + nn] = BPACK ? bu[i] : cvt_one_pack(bf[i]);
        }
    };

    f32x4 acc[MT];
    #pragma unroll
    for (int i = 0; i < MT; i++) acc[i] = (f32x4){0.f, 0.f, 0.f, 0.f};

    auto computeTile = [&](const unsigned int* sm) {
        const unsigned int* Ah = sm;
        const unsigned int* Al = sm + ASZ;
        f16x8 fbh, fbl;
        if constexpr (BT) {
            const unsigned int* Bh = sm + 2 * ASZ;
            const unsigned int* Bl = Bh + 64 * AP;
            int row = w * 16 + fr;
            fbh = __builtin_bit_cast(f16x8, *(const u32x4*)&Bh[row * AP + g * 4]);
            fbl = __builtin_bit_cast(f16x8, *(const u32x4*)&Bl[row * AP + g * 4]);
        } else {
            const unsigned int* Bp = sm + 2 * ASZ;
            unsigned int p[8];
            #pragma unroll
            for (int j = 0; j < 8; j++)
                p[j] = Bp[(g * 8 + j) * BP_NN + w * 16 + fr];
            unsigned int hu[4], lu[4];
            #pragma unroll
            for (int r = 0; r < 4; r++) {
                hu[r] = __builtin_amdgcn_perm(p[2 * r + 1], p[2 * r], PERM_HI);
                lu[r] = __builtin_amdgcn_perm(p[2 * r + 1], p[2 * r], PERM_LO);
            }
            fbh = __builtin_bit_cast(f16x8, (u32x4){hu[0], hu[1], hu[2], hu[3]});
            fbl = __builtin_bit_cast(f16x8, (u32x4){lu[0], lu[1], lu[2], lu[3]});
        }
        #pragma unroll
        for (int mt = 0; mt < MT; mt++) {
            int row = fr + 16 * mt;
            f16x8 fah = __builtin_bit_cast(f16x8, *(const u32x4*)&Ah[row * AP + g * 4]);
            f16x8 fal = __builtin_bit_cast(f16x8, *(const u32x4*)&Al[row * AP + g * 4]);
            acc[mt] = __builtin_amdgcn_mfma_f32_16x16x32_f16(fah, fbh, acc[mt], 0, 0, 0);
            acc[mt] = __builtin_amdgcn_mfma_f32_16x16x32_f16(fal, fbh, acc[mt], 0, 0, 0);
            acc[mt] = __builtin_amdgcn_mfma_f32_16x16x32_f16(fah, fbl, acc[mt], 0, 0, 0);
        }
    };

    // ---- double-buffered main loop: 1 barrier/iter ----
    const int nt = Kdim >> 5;
    stageA(0); stageB(0);
    storeStage(smem);
    __syncthreads();
    for (int tt = 0; tt < nt; tt++) {
        unsigned int* cur = smem + (tt & 1) * HALF;
        unsigned int* nxt = smem + ((tt + 1) & 1) * HALF;
        const bool more = (tt + 1 < nt);
        if (more) { stageA((tt + 1) << 5); stageB((tt + 1) << 5); }
        computeTile(cur);
        if (more) storeStage(nxt);   // targets buffer consumed at tt-1: safe
        __syncthreads();
    }

    // ---- epilogue ----
    const int col = n0 + w * 16 + fr;
    if constexpr (EPI == 0) {
        unsigned int* Cb = C + (long)b * sC;
        #pragma unroll
        for (int mt = 0; mt < MT; mt++)
            #pragma unroll
            for (int r = 0; r < 4; r++)
                Cb[(long)(m0 + mt * 16 + g * 4 + r) * Ndim + col] = cvt_one_pack(acc[mt][r]);
    } else if constexpr (EPI == 2) {
        unsigned int* Cb = C + (long)b * sC;
        float s = 0.f;
        #pragma unroll
        for (int mt = 0; mt < 2; mt++)
            #pragma unroll
            for (int r = 0; r < 4; r++) {
                int row = mt * 16 + g * 4 + r;
                Cb[(long)row * Ndim + col] = cvt_one_pack(acc[mt][r]);
                s += wsh[row] * tanhf(acc[mt][r] + acc[mt + 2][r]);
            }
        s += __shfl_xor(s, 16, 64);
        s += __shfl_xor(s, 32, 64);
        if (g == 0) Yout[(long)b * Ndim + col] = s;
    } else {  // EPI == 3
        const unsigned int* Xb = Xadd + (long)b * sC;
        float s = 0.f;
        #pragma unroll
        for (int mt = 0; mt < MT; mt++)
            #pragma unroll
            for (int r = 0; r < 4; r++) {
                int row = mt * 16 + g * 4 + r;
                float x = unpacksplit(Xb[(long)row * Ndim + col]);
                s += wsh[row] * tanhf(x + acc[mt][r]);
            }
        s += __shfl_xor(s, 16, 64);
        s += __shfl_xor(s, 32, 64);
        if (g == 0) Yout[(long)b * Ndim + col] = s;
    }
}

// ---------------------------------------------------------------------------
// fused softmax(sv[b,:]) + poolv: v1[b,e] = Sum_m a_v[b,m] * V[b,e,m]
// grid (4, Bn) x 1024 thr.
// ---------------------------------------------------------------------------
__global__ __launch_bounds__(1024) void smpool_v_kernel(
    const float* __restrict__ sv, const float* __restrict__ V,
    float* __restrict__ v1)
{
    const int b = blockIdx.y, qtr = blockIdx.x, t = threadIdx.x;
    const int wid = t >> 6, lane = t & 63;
    __shared__ float red[16];
    __shared__ float bc;
    __shared__ float av[Mn];

    float x = sv[(long)b * Mn + t];
    float v = x;
    #pragma unroll
    for (int off = 32; off > 0; off >>= 1) v = fmaxf(v, __shfl_down(v, off, 64));
    if (lane == 0) red[wid] = v;
    __syncthreads();
    if (t == 0) {
        float m = red[0];
        for (int i = 1; i < 16; i++) m = fmaxf(m, red[i]);
        bc = m;
    }
    __syncthreads();
    float e = expf(x - bc);
    v = e;
    #pragma unroll
    for (int off = 32; off > 0; off >>= 1) v += __shfl_down(v, off, 64);
    if (lane == 0) red[wid] = v;
    __syncthreads();
    if (t == 0) {
        float s = 0.f;
        for (int i = 0; i < 16; i++) s += red[i];
        bc = s;
    }
    __syncthreads();
    av[t] = e / bc;
    __syncthreads();

    f32x4 aa[4];
    #pragma unroll
    for (int i = 0; i < 4; i++) aa[i] = *(const f32x4*)&av[4 * (lane + 64 * i)];

    #pragma unroll
    for (int j = 0; j < 8; j++) {
        int e_ = qtr * 128 + wid * 8 + j;
        const float* vr = V + ((long)b * Dn + e_) * Mn;
        float acc = 0.f;
        #pragma unroll
        for (int i = 0; i < 4; i++) {
            f32x4 vv = *(const f32x4*)&vr[4 * (lane + 64 * i)];
            acc += vv.x * aa[i].x + vv.y * aa[i].y + vv.z * aa[i].z + vv.w * aa[i].w;
        }
        #pragma unroll
        for (int off = 32; off > 0; off >>= 1) acc += __shfl_down(acc, off, 64);
        if (lane == 0) v1[(long)b * Dn + e_] = acc;
    }
}

// ---------------------------------------------------------------------------
// fused softmax(sq[b,:]) + poolq: q1[b,e] = Sum_l a_q[b,l] * Q[b,l,e]
// grid (8, Bn) x 256 thr; 4 threads per output e.
// ---------------------------------------------------------------------------
__global__ __launch_bounds__(256) void smpool_q_kernel(
    const float* __restrict__ sq, const float* __restrict__ Q,
    float* __restrict__ q1)
{
    const int b = blockIdx.y, eb = blockIdx.x, t = threadIdx.x;
    const int wid = t >> 6, lane = t & 63;
    __shared__ float red[4];
    __shared__ float bc;
    __shared__ float aq[Ln];

    float x = sq[(long)b * Ln + t];
    float v = x;
    #pragma unroll
    for (int off = 32; off > 0; off >>= 1) v = fmaxf(v, __shfl_down(v, off, 64));
    if (lane == 0) red[wid] = v;
    __syncthreads();
    if (t == 0) {
        float m = red[0];
        for (int i = 1; i < 4; i++) m = fmaxf(m, red[i]);
        bc = m;
    }
    __syncthreads();
    float e = expf(x - bc);
    v = e;
    #pragma unroll
    for (int off = 32; off > 0; off >>= 1) v += __shfl_down(v, off, 64);
    if (lane == 0) red[wid] = v;
    __syncthreads();
    if (t == 0) {
        float s = 0.f;
        for (int i = 0; i < 4; i++) s += red[i];
        bc = s;
    }
    __syncthreads();
    aq[t] = e / bc;
    __syncthreads();

    const int e_ = eb * 64 + (t >> 2), qtr = t & 3;
    const float* Qb = Q + (long)b * Ln * Dn;
    float acc = 0.f;
    #pragma unroll 4
    for (int i = 0; i < 64; i++) {
        int l = qtr * 64 + i;
        acc += aq[l] * Qb[(long)l * Dn + e_];
    }
    acc += __shfl_xor(acc, 1, 64);
    acc += __shfl_xor(acc, 2, 64);
    if (qtr == 0) q1[(long)b * Dn + e_] = acc;
}

// ---------------------------------------------------------------------------
// Broadcast outputs
// ---------------------------------------------------------------------------
__global__ void bcast_kernel(const float* __restrict__ v1,
                             const float* __restrict__ q1,
                             float* __restrict__ out)
{
    const long nv4 = (long)Bn * Mn * Dn / 4;
    const long nq4 = (long)Bn * Ln * Dn / 4;
    long idx = (long)blockIdx.x * blockDim.x + threadIdx.x;
    float4* o4 = (float4*)out;
    if (idx < nv4) {
        long fidx = idx * 4;
        int e4 = (int)(fidx & (Dn - 1));
        long bm = fidx >> 9;
        int b = (int)(bm >> 10);
        o4[idx] = *(const float4*)(v1 + (long)b * Dn + e4);
    } else if (idx < nv4 + nq4) {
        long fidx = (idx - nv4) * 4;
        int e4 = (int)(fidx & (Dn - 1));
        long bl = fidx >> 9;
        int b = (int)(bl >> 8);
        o4[idx] = *(const float4*)(q1 + (long)b * Dn + e4);
    }
}

// ---------------------------------------------------------------------------

extern "C" void kernel_launch(void* const* d_in, const int* in_sizes, int n_in,
                              void* d_out, int out_size, void* d_ws, size_t ws_size,
                              hipStream_t stream)
{
    const float* V    = (const float*)d_in[0];  // [B, d, M]
    const float* Q    = (const float*)d_in[1];  // [B, L, d]
    const float* W_b  = (const float*)d_in[2];  // [d, d]
    const float* W_v  = (const float*)d_in[3];  // [K, d]
    const float* W_q  = (const float*)d_in[4];  // [K, d]
    const float* w_hv = (const float*)d_in[5];  // [K, 1]
    const float* w_hq = (const float*)d_in[6];  // [K, 1]
    float* out = (float*)d_out;

    // workspace (u32 elements)
    const long nQ  = (long)Bn * Ln * Dn;   // 8388608
    const long nWb = (long)Dn * Dn;        // 262144
    const long nWq = (long)Kn * Dn;        // 15360
    const long nWv = (long)Kn * Dn;        // 15360
    const long szWqQ = (long)Bn * KP * Ln; // 524288
    const long szU   = (long)Bn * KP * Dn; // 1048576
    const long szSo  = (long)Bn * KP * Mn; // 2097152

    unsigned int* wsu   = (unsigned int*)d_ws;
    unsigned int* Qp    = wsu;
    unsigned int* Wbp   = Qp    + nQ;
    unsigned int* Wqp   = Wbp   + nWb;
    unsigned int* Wvp   = Wqp   + nWq;
    unsigned int* WqQp  = Wvp   + nWv;
    unsigned int* Up    = WqQp  + szWqQ;
    unsigned int* Pp    = Up    + szU;
    unsigned int* Soutp = Pp    + szU;
    unsigned int* Rp    = Soutp + szSo;
    unsigned int* Gp    = Rp    + szU;
    float* sv = (float*)(Gp + szU);
    float* sq = sv + (long)Bn * Mn;
    float* v1 = sq + (long)Bn * Ln;
    float* q1 = v1 + (long)Bn * Dn;

    // p0. one-shot pack of Q, W_b, W_q, W_v
    pack4_kernel<<<4096, 256, 0, stream>>>(
        Q, Qp, nQ, W_b, Wbp, nWb, W_q, Wqp, nWq, W_v, Wvp, nWv);

    // g1. WqQ[b] = Wq @ Q[b]^T : NT, M=30, N=256, K=512
    fgemm_kernel<2, true, 0, true, 0><<<dim3(4, 1, 64), 256, 0, stream>>>(
        Wqp, Qp, nullptr, WqQp, nullptr, nullptr, nullptr,
        Kn, Ln, Dn, Dn, Dn, 0, (long)Ln * Dn, (long)KP * Ln);

    // g2. U[b] = WqQ[b] @ Q[b] : NN, M=32, N=512, K=256
    fgemm_kernel<2, false, 0, true, 0><<<dim3(8, 1, 64), 256, 0, stream>>>(
        WqQp, Qp, nullptr, Up, nullptr, nullptr, nullptr,
        KP, Dn, Ln, Ln, Dn, (long)KP * Ln, (long)Ln * Dn, (long)KP * Dn);

    // g3. P = Uflat[2048,512] @ W_b : NN
    fgemm_kernel<4, false, 0, true, 0><<<dim3(8, 32, 1), 256, 0, stream>>>(
        Up, Wbp, nullptr, Pp, nullptr, nullptr, nullptr,
        Bn * KP, Dn, Dn, Dn, Dn, 0, 0, 0);

    // g5. Sout[b](rows<32) = ([W_v;0;P[b]] @ V[b]) : NN, M=64, N=1024, K=512
    //     A concat (ASRC=2), B = V fp32; sv fused (EPI=2).
    fgemm_kernel<4, false, 2, false, 2><<<dim3(16, 1, 64), 256, 0, stream>>>(
        Wvp, V, Pp, Soutp, w_hv, nullptr, sv,
        64, Mn, Dn, Dn, Mn, 0, (long)Dn * Mn, (long)KP * Mn);

    // g7. R[b,k,e] = Sum_m Sout[k,m] V[e,m] : NT, M=32, N=512, K=1024
    fgemm_kernel<2, true, 0, false, 0><<<dim3(8, 1, 64), 256, 0, stream>>>(
        Soutp, V, nullptr, Rp, nullptr, nullptr, nullptr,
        KP, Dn, Mn, Mn, Mn, (long)KP * Mn, (long)Dn * Mn, (long)KP * Dn);

    // g8. G = Rflat[2048,512] @ W_b^T : NT
    fgemm_kernel<4, true, 0, true, 0><<<dim3(8, 32, 1), 256, 0, stream>>>(
        Rp, Wbp, nullptr, Gp, nullptr, nullptr, nullptr,
        Bn * KP, Dn, Dn, Dn, Dn, 0, 0, 0);

    // g9. Tq = G @ Q^T : NT, M=32, N=256, K=512; sq fused (EPI=3), X = WqQp
    fgemm_kernel<2, true, 3, true, 0><<<dim3(4, 1, 64), 256, 0, stream>>>(
        Gp, Qp, nullptr, nullptr, w_hq, WqQp, sq,
        KP, Ln, Dn, Dn, Dn, (long)KP * Dn, (long)Ln * Dn, (long)KP * Ln);

    // softmax + pools
    smpool_v_kernel<<<dim3(4, Bn), 1024, 0, stream>>>(sv, V, v1);
    smpool_q_kernel<<<dim3(8, Bn), 256, 0, stream>>>(sq, Q, q1);

    // broadcast outputs
    {
        long n4 = (long)Bn * Mn * Dn / 4 + (long)Bn * Ln * Dn / 4;
        bcast_kernel<<<(int)((n4 + 255) / 256), 256, 0, stream>>>(v1, q1, out);
    }
}

// Round 6
// 448.129 us; speedup vs baseline: 1.4678x; 1.0083x over previous
//
#include <hip/hip_runtime.h>

// Problem dims
constexpr int Bn = 64;     // batch
constexpr int Dn = 512;    // embed dim
constexpr int Mn = 1024;   // M
constexpr int Ln = 256;    // L
constexpr int Kn = 30;     // K heads
constexpr int KP = 32;     // K padded to 32 rows

typedef __attribute__((ext_vector_type(4))) float f32x4;
typedef __attribute__((ext_vector_type(2))) float f32x2;
typedef __attribute__((ext_vector_type(4))) unsigned int u32x4;
typedef __attribute__((ext_vector_type(2))) unsigned int u32x2;
typedef __attribute__((ext_vector_type(8))) _Float16 f16x8;
typedef __attribute__((ext_vector_type(2))) _Float16 f16x2;
typedef unsigned short ushort_t;

// ---------------------------------------------------------------------------
// split-fp16 packed format: u32 = (hi<<16) | lo, x = hi + lo (~22 mantissa
// bits). All values well inside fp16 normal range (max ~4e3 << 65504).
// ---------------------------------------------------------------------------
__device__ __forceinline__ unsigned int cvt_one_pack(float x)
{
    _Float16 h = (_Float16)x;
    _Float16 l = (_Float16)(x - (float)h);
    return (unsigned int)__builtin_bit_cast(ushort_t, l) |
           ((unsigned int)__builtin_bit_cast(ushort_t, h) << 16);
}

__device__ __forceinline__ float unpacksplit(unsigned int p)
{
    _Float16 h = __builtin_bit_cast(_Float16, (ushort_t)(p >> 16));
    _Float16 l = __builtin_bit_cast(_Float16, (ushort_t)(p & 0xffffu));
    return (float)h + (float)l;
}

__device__ __forceinline__ void cvt_pair(float a, float b,
                                         unsigned int& hp, unsigned int& lp)
{
    _Float16 ha = (_Float16)a, hb = (_Float16)b;
    _Float16 la = (_Float16)(a - (float)ha), lb = (_Float16)(b - (float)hb);
    f16x2 hv = {ha, hb}, lv = {la, lb};
    hp = __builtin_bit_cast(unsigned int, hv);
    lp = __builtin_bit_cast(unsigned int, lv);
}

// perm: from packed pair (p0=(h0<<16)|l0, p1=(h1<<16)|l1)
//   perm(p1,p0,PERM_HI) = (h1<<16)|h0 ; perm(p1,p0,PERM_LO) = (l1<<16)|l0
#define PERM_HI 0x07060302u
#define PERM_LO 0x05040100u

// ---------------------------------------------------------------------------
// LDS geometry for fgemm
// ---------------------------------------------------------------------------
template <int MT, bool BT> struct LdsCfg {
    static constexpr int AP    = 20;            // u32 pitch (16 data + 4 pad)
    static constexpr int ASZ   = MT * 16 * AP;  // one A plane
    static constexpr int BP_NN = 66;            // NN packed pitch
    static constexpr int BSZ   = BT ? (2 * 64 * AP) : (32 * BP_NN);
    static constexpr int HALF  = 2 * ASZ + BSZ;
    static constexpr int TOT   = 2 * HALF + 32; // + wsh[32]
};

// ---------------------------------------------------------------------------
// Split-fp16 MFMA GEMM device body, LDS double-buffer, 1 barrier/iter.
//   C[b][M][N] = A @ B ; B always fp32 (converted in staging).
//     NN (BT=false): B[b] is [K][N] row-major, row stride ldB
//     NT (BT=true):  B[b] is [N][K] row-major, row stride ldB
//   AF32: A is fp32 (convert in staging) vs packed u32.
//   ASRC: 0 = plain A (rows >= Mreal read 0); 2 = concat: rows<30 from A
//         (=W_v fp32), 30-31 zero, rows>=32 from A2 packed at
//         A2[(b*32+row-32)*ldA].
//   BM = MT*16, BN = 64, BK = 32, 256 thr = 4 waves, wave w owns cols
//   [w*16,w*16+16).
//   EPI: 0 = packed C write
//        2 = SV: packed C rows<32; sv[b,col] = sum_k w[k]*tanh(acc_k +
//             acc_{k+32}) shfl-reduced (MT=4)
//        3 = SQ: no C; sq[b,col] = sum_k w[k]*tanh(unpack(X)+acc_k) (MT=2,
//             sC = X batch stride)
// ---------------------------------------------------------------------------
template <int MT, bool BT, int EPI, bool AF32, int ASRC>
__device__ __forceinline__ void fgemm_dev(
    unsigned int* smem, int nb, int mb, int b,
    const void* Av, const float* B, const unsigned int* A2,
    unsigned int* C, const float* Wvec, const unsigned int* Xadd,
    float* Yout,
    int Mreal, int Ndim, int Kdim, int ldA, int ldB,
    long sA, long sB, long sC)
{
    using L = LdsCfg<MT, BT>;
    constexpr int AP = L::AP, ASZ = L::ASZ, BP_NN = L::BP_NN, HALF = L::HALF;
    float* wsh = (float*)(smem + 2 * HALF);

    const int t  = threadIdx.x;
    const int n0 = nb * 64;
    const int m0 = mb * MT * 16;
    const float*        Afb = (const float*)Av + (long)b * sA;
    const unsigned int* Aub = (const unsigned int*)Av + (long)b * sA;
    const float*        Bb  = B + (long)b * sB;

    const int lane = t & 63, w = t >> 6;
    const int fr = lane & 15, g = lane >> 4;
    const int kp  = t & 15, r16 = t >> 4;       // 16 threads per row staging
    const int nn  = t & 63, kr  = t >> 6;       // NN B staging

    if (EPI >= 2 && t < 32) wsh[t] = (t < Kn) ? Wvec[t] : 0.f;

    float asf[MT][2];
    unsigned int aA[MT][2];
    float bf[8];

    auto stageA = [&](int k0) {
        #pragma unroll
        for (int i = 0; i < MT; i++) {
            int gm = m0 + r16 + 16 * i;
            if constexpr (ASRC == 2) {
                if (gm < Kn) {
                    f32x2 v = *(const f32x2*)&((const float*)Av)[(long)gm * ldA + k0 + 2 * kp];
                    asf[i][0] = v.x; asf[i][1] = v.y;
                } else if (gm >= 32) {
                    u32x2 v = *(const u32x2*)&A2[((long)b * 32 + gm - 32) * ldA + k0 + 2 * kp];
                    aA[i][0] = v.x; aA[i][1] = v.y;
                } else {
                    asf[i][0] = 0.f; asf[i][1] = 0.f;
                }
            } else if constexpr (AF32) {
                float x0 = 0.f, x1 = 0.f;
                if (gm < Mreal) {
                    f32x2 v = *(const f32x2*)&Afb[(long)gm * ldA + k0 + 2 * kp];
                    x0 = v.x; x1 = v.y;
                }
                asf[i][0] = x0; asf[i][1] = x1;
            } else {
                unsigned int p0 = 0, p1 = 0;
                if (gm < Mreal) {
                    u32x2 v = *(const u32x2*)&Aub[(long)gm * ldA + k0 + 2 * kp];
                    p0 = v.x; p1 = v.y;
                }
                aA[i][0] = p0; aA[i][1] = p1;
            }
        }
    };
    auto stageB = [&](int k0) {
        if constexpr (BT) {
            #pragma unroll
            for (int i = 0; i < 4; i++) {
                f32x2 v = *(const f32x2*)&Bb[(long)(n0 + r16 + 16 * i) * ldB + k0 + 2 * kp];
                bf[2 * i] = v.x; bf[2 * i + 1] = v.y;
            }
        } else {
            #pragma unroll
            for (int i = 0; i < 8; i++)
                bf[i] = Bb[(long)(k0 + kr + 4 * i) * ldB + n0 + nn];
        }
    };
    auto storeStage = [&](unsigned int* sm) {
        unsigned int* Ah = sm;
        unsigned int* Al = sm + ASZ;
        #pragma unroll
        for (int i = 0; i < MT; i++) {
            unsigned int hp, lp;
            if constexpr (ASRC == 2) {
                int gm = m0 + r16 + 16 * i;
                if (gm < 32) cvt_pair(asf[i][0], asf[i][1], hp, lp);
                else {
                    hp = __builtin_amdgcn_perm(aA[i][1], aA[i][0], PERM_HI);
                    lp = __builtin_amdgcn_perm(aA[i][1], aA[i][0], PERM_LO);
                }
            } else if constexpr (AF32) {
                cvt_pair(asf[i][0], asf[i][1], hp, lp);
            } else {
                hp = __builtin_amdgcn_perm(aA[i][1], aA[i][0], PERM_HI);
                lp = __builtin_amdgcn_perm(aA[i][1], aA[i][0], PERM_LO);
            }
            Ah[(r16 + 16 * i) * AP + kp] = hp;
            Al[(r16 + 16 * i) * AP + kp] = lp;
        }
        if constexpr (BT) {
            unsigned int* Bh = sm + 2 * ASZ;
            unsigned int* Bl = Bh + 64 * AP;
            #pragma unroll
            for (int i = 0; i < 4; i++) {
                unsigned int hp, lp;
                cvt_pair(bf[2 * i], bf[2 * i + 1], hp, lp);
                Bh[(r16 + 16 * i) * AP + kp] = hp;
                Bl[(r16 + 16 * i) * AP + kp] = lp;
            }
        } else {
            unsigned int* Bp = sm + 2 * ASZ;
            #pragma unroll
            for (int i = 0; i < 8; i++)
                Bp[(kr + 4 * i) * BP_NN + nn] = cvt_one_pack(bf[i]);
        }
    };

    f32x4 acc[MT];
    #pragma unroll
    for (int i = 0; i < MT; i++) acc[i] = (f32x4){0.f, 0.f, 0.f, 0.f};

    auto computeTile = [&](const unsigned int* sm) {
        const unsigned int* Ah = sm;
        const unsigned int* Al = sm + ASZ;
        f16x8 fbh, fbl;
        if constexpr (BT) {
            const unsigned int* Bh = sm + 2 * ASZ;
            const unsigned int* Bl = Bh + 64 * AP;
            int row = w * 16 + fr;
            fbh = __builtin_bit_cast(f16x8, *(const u32x4*)&Bh[row * AP + g * 4]);
            fbl = __builtin_bit_cast(f16x8, *(const u32x4*)&Bl[row * AP + g * 4]);
        } else {
            const unsigned int* Bp = sm + 2 * ASZ;
            unsigned int p[8];
            #pragma unroll
            for (int j = 0; j < 8; j++)
                p[j] = Bp[(g * 8 + j) * BP_NN + w * 16 + fr];
            unsigned int hu[4], lu[4];
            #pragma unroll
            for (int r = 0; r < 4; r++) {
                hu[r] = __builtin_amdgcn_perm(p[2 * r + 1], p[2 * r], PERM_HI);
                lu[r] = __builtin_amdgcn_perm(p[2 * r + 1], p[2 * r], PERM_LO);
            }
            fbh = __builtin_bit_cast(f16x8, (u32x4){hu[0], hu[1], hu[2], hu[3]});
            fbl = __builtin_bit_cast(f16x8, (u32x4){lu[0], lu[1], lu[2], lu[3]});
        }
        #pragma unroll
        for (int mt = 0; mt < MT; mt++) {
            int row = fr + 16 * mt;
            f16x8 fah = __builtin_bit_cast(f16x8, *(const u32x4*)&Ah[row * AP + g * 4]);
            f16x8 fal = __builtin_bit_cast(f16x8, *(const u32x4*)&Al[row * AP + g * 4]);
            acc[mt] = __builtin_amdgcn_mfma_f32_16x16x32_f16(fah, fbh, acc[mt], 0, 0, 0);
            acc[mt] = __builtin_amdgcn_mfma_f32_16x16x32_f16(fal, fbh, acc[mt], 0, 0, 0);
            acc[mt] = __builtin_amdgcn_mfma_f32_16x16x32_f16(fah, fbl, acc[mt], 0, 0, 0);
        }
    };

    // ---- double-buffered main loop: 1 barrier/iter ----
    const int nt = Kdim >> 5;
    stageA(0); stageB(0);
    storeStage(smem);
    __syncthreads();
    for (int tt = 0; tt < nt; tt++) {
        unsigned int* cur = smem + (tt & 1) * HALF;
        unsigned int* nxt = smem + ((tt + 1) & 1) * HALF;
        const bool more = (tt + 1 < nt);
        if (more) { stageA((tt + 1) << 5); stageB((tt + 1) << 5); }
        computeTile(cur);
        if (more) storeStage(nxt);   // buffer consumed at tt-1: safe
        __syncthreads();
    }

    // ---- epilogue ----
    const int col = n0 + w * 16 + fr;
    if constexpr (EPI == 0) {
        unsigned int* Cb = C + (long)b * sC;
        #pragma unroll
        for (int mt = 0; mt < MT; mt++)
            #pragma unroll
            for (int r = 0; r < 4; r++)
                Cb[(long)(m0 + mt * 16 + g * 4 + r) * Ndim + col] = cvt_one_pack(acc[mt][r]);
    } else if constexpr (EPI == 2) {
        unsigned int* Cb = C + (long)b * sC;
        float s = 0.f;
        #pragma unroll
        for (int mt = 0; mt < 2; mt++)
            #pragma unroll
            for (int r = 0; r < 4; r++) {
                int row = mt * 16 + g * 4 + r;
                Cb[(long)row * Ndim + col] = cvt_one_pack(acc[mt][r]);
                s += wsh[row] * tanhf(acc[mt][r] + acc[mt + 2][r]);
            }
        s += __shfl_xor(s, 16, 64);
        s += __shfl_xor(s, 32, 64);
        if (g == 0) Yout[(long)b * Ndim + col] = s;
    } else {  // EPI == 3
        const unsigned int* Xb = Xadd + (long)b * sC;
        float s = 0.f;
        #pragma unroll
        for (int mt = 0; mt < MT; mt++)
            #pragma unroll
            for (int r = 0; r < 4; r++) {
                int row = mt * 16 + g * 4 + r;
                float x = unpacksplit(Xb[(long)row * Ndim + col]);
                s += wsh[row] * tanhf(x + acc[mt][r]);
            }
        s += __shfl_xor(s, 16, 64);
        s += __shfl_xor(s, 32, 64);
        if (g == 0) Yout[(long)b * Ndim + col] = s;
    }
}

template <int MT, bool BT, int EPI, bool AF32, int ASRC>
__global__ __launch_bounds__(256) void fgemm_kernel(
    const void* A, const float* B, const unsigned int* A2,
    unsigned int* C, const float* Wvec, const unsigned int* Xadd,
    float* Yout,
    int Mreal, int Ndim, int Kdim, int ldA, int ldB,
    long sA, long sB, long sC)
{
    __shared__ unsigned int smem[LdsCfg<MT, BT>::TOT];
    fgemm_dev<MT, BT, EPI, AF32, ASRC>(smem, blockIdx.x, blockIdx.y, blockIdx.z,
        A, B, A2, C, Wvec, Xadd, Yout, Mreal, Ndim, Kdim, ldA, ldB, sA, sB, sC);
}

// ---------------------------------------------------------------------------
// smv body: softmax(sv[b,:]) + pool 64 e's + write broadcast rows of out_v.
// 256 threads. sm: av[1024] | ev[64] | red[4] | bc[1]
// ---------------------------------------------------------------------------
__device__ __forceinline__ void smv_body(float* sm, int eb, int b,
    const float* __restrict__ sv, const float* __restrict__ V,
    float* __restrict__ outv)
{
    float* av  = sm;
    float* ev  = sm + 1024;
    float* red = sm + 1088;
    float* bcp = sm + 1092;
    const int t = threadIdx.x, lane = t & 63, w = t >> 6;
    const int e0 = eb * 64;

    f32x4 x4 = *(const f32x4*)&sv[(long)b * Mn + 4 * t];
    float mx = fmaxf(fmaxf(x4.x, x4.y), fmaxf(x4.z, x4.w));
    #pragma unroll
    for (int off = 32; off > 0; off >>= 1) mx = fmaxf(mx, __shfl_down(mx, off, 64));
    if (lane == 0) red[w] = mx;
    __syncthreads();
    if (t == 0) bcp[0] = fmaxf(fmaxf(red[0], red[1]), fmaxf(red[2], red[3]));
    __syncthreads();
    const float m = bcp[0];
    f32x4 e4 = {expf(x4.x - m), expf(x4.y - m), expf(x4.z - m), expf(x4.w - m)};
    *(f32x4*)&av[4 * t] = e4;
    float se = e4.x + e4.y + e4.z + e4.w;
    #pragma unroll
    for (int off = 32; off > 0; off >>= 1) se += __shfl_down(se, off, 64);
    if (lane == 0) red[w] = se;
    __syncthreads();
    if (t == 0) bcp[0] = 1.f / (red[0] + red[1] + red[2] + red[3]);
    __syncthreads();
    const float rinv = bcp[0];

    f32x4 aa[4];
    #pragma unroll
    for (int i = 0; i < 4; i++) aa[i] = *(const f32x4*)&av[4 * (lane + 64 * i)];

    for (int i = 0; i < 16; i++) {
        int el = w * 16 + i;
        const float* vr = V + ((long)b * Dn + e0 + el) * Mn;
        float acc = 0.f;
        #pragma unroll
        for (int s = 0; s < 4; s++) {
            f32x4 v4 = *(const f32x4*)&vr[4 * (lane + 64 * s)];
            acc += v4.x * aa[s].x + v4.y * aa[s].y + v4.z * aa[s].z + v4.w * aa[s].w;
        }
        #pragma unroll
        for (int off = 32; off > 0; off >>= 1) acc += __shfl_down(acc, off, 64);
        if (lane == 0) ev[el] = acc * rinv;
    }
    __syncthreads();

    const int c4 = t & 15;
    f32x4 ev4 = ((const f32x4*)ev)[c4];
    #pragma unroll 4
    for (int rep = 0; rep < 64; rep++) {
        int row = rep * 16 + (t >> 4);
        *(f32x4*)&outv[((long)b * Mn + row) * Dn + e0 + 4 * c4] = ev4;
    }
}

// ---------------------------------------------------------------------------
// Fat kernel: blockIdx.x < 8 -> g7 (R = Sout @ V^T), >= 8 -> smv pooling.
// ---------------------------------------------------------------------------
__global__ __launch_bounds__(256) void g7smv_kernel(
    const unsigned int* __restrict__ Soutp, const float* __restrict__ V,
    unsigned int* __restrict__ Rp, const float* __restrict__ sv,
    float* __restrict__ outv)
{
    constexpr int TOT = LdsCfg<2, true>::TOT;   // 7712 >= 1093
    __shared__ unsigned int smem[TOT];
    if (blockIdx.x < 8) {
        fgemm_dev<2, true, 0, false, 0>(smem, blockIdx.x, 0, blockIdx.z,
            Soutp, V, nullptr, Rp, nullptr, nullptr, nullptr,
            KP, Dn, Mn, Mn, Mn,
            (long)KP * Mn, (long)Dn * Mn, (long)KP * Dn);
    } else {
        smv_body((float*)smem, blockIdx.x - 8, blockIdx.z, sv, V, outv);
    }
}

// ---------------------------------------------------------------------------
// smq: softmax(sq[b,:]) + pool 64 e's + write broadcast rows of out_q.
// grid (8, Bn) x 256 thr.
// ---------------------------------------------------------------------------
__global__ __launch_bounds__(256) void smq_out_kernel(
    const float* __restrict__ sq, const float* __restrict__ Q,
    float* __restrict__ outq)
{
    __shared__ float sm[326];
    float* aq  = sm;         // 256
    float* ev  = sm + 256;   // 64
    float* red = sm + 320;   // 4
    float* bcp = sm + 324;
    const int b = blockIdx.y, eb = blockIdx.x, t = threadIdx.x;
    const int lane = t & 63, w = t >> 6;
    const int e0 = eb * 64;

    float x = sq[(long)b * Ln + t];
    float mx = x;
    #pragma unroll
    for (int off = 32; off > 0; off >>= 1) mx = fmaxf(mx, __shfl_down(mx, off, 64));
    if (lane == 0) red[w] = mx;
    __syncthreads();
    if (t == 0) bcp[0] = fmaxf(fmaxf(red[0], red[1]), fmaxf(red[2], red[3]));
    __syncthreads();
    const float m = bcp[0];
    float e = expf(x - m);
    aq[t] = e;
    float se = e;
    #pragma unroll
    for (int off = 32; off > 0; off >>= 1) se += __shfl_down(se, off, 64);
    if (lane == 0) red[w] = se;
    __syncthreads();
    if (t == 0) bcp[0] = 1.f / (red[0] + red[1] + red[2] + red[3]);
    __syncthreads();
    const float rinv = bcp[0];

    const int e_l = t >> 2, qtr = t & 3;
    const float* Qb = Q + (long)b * Ln * Dn;
    float acc = 0.f;
    #pragma unroll 4
    for (int i = 0; i < 64; i++) {
        int l = qtr * 64 + i;
        acc += aq[l] * Qb[(long)l * Dn + e0 + e_l];
    }
    acc += __shfl_xor(acc, 1, 64);
    acc += __shfl_xor(acc, 2, 64);
    if (qtr == 0) ev[e_l] = acc * rinv;
    __syncthreads();

    const int c4 = t & 15;
    f32x4 ev4 = ((const f32x4*)ev)[c4];
    #pragma unroll 4
    for (int rep = 0; rep < 16; rep++) {
        int row = rep * 16 + (t >> 4);
        *(f32x4*)&outq[((long)b * Ln + row) * Dn + e0 + 4 * c4] = ev4;
    }
}

// ---------------------------------------------------------------------------

extern "C" void kernel_launch(void* const* d_in, const int* in_sizes, int n_in,
                              void* d_out, int out_size, void* d_ws, size_t ws_size,
                              hipStream_t stream)
{
    const float* V    = (const float*)d_in[0];  // [B, d, M]
    const float* Q    = (const float*)d_in[1];  // [B, L, d]
    const float* W_b  = (const float*)d_in[2];  // [d, d]
    const float* W_v  = (const float*)d_in[3];  // [K, d]
    const float* W_q  = (const float*)d_in[4];  // [K, d]
    const float* w_hv = (const float*)d_in[5];  // [K, 1]
    const float* w_hq = (const float*)d_in[6];  // [K, 1]
    float* out = (float*)d_out;

    // workspace (u32 elements)
    const long szWqQ = (long)Bn * KP * Ln; // 524288
    const long szU   = (long)Bn * KP * Dn; // 1048576
    const long szSo  = (long)Bn * KP * Mn; // 2097152

    unsigned int* wsu   = (unsigned int*)d_ws;
    unsigned int* WqQp  = wsu;
    unsigned int* Up    = WqQp  + szWqQ;
    unsigned int* Pp    = Up    + szU;
    unsigned int* Soutp = Pp    + szU;
    unsigned int* Rp    = Soutp + szSo;
    unsigned int* Gp    = Rp    + szU;
    float* sv = (float*)(Gp + szU);
    float* sq = sv + (long)Bn * Mn;

    float* outv = out;
    float* outq = out + (long)Bn * Mn * Dn;

    // g1. WqQ[b] = Wq @ Q[b]^T : NT, M=30, N=256, K=512 (A fp32)
    fgemm_kernel<2, true, 0, true, 0><<<dim3(4, 1, 64), 256, 0, stream>>>(
        W_q, Q, nullptr, WqQp, nullptr, nullptr, nullptr,
        Kn, Ln, Dn, Dn, Dn, 0, (long)Ln * Dn, (long)KP * Ln);

    // g2. U[b] = WqQ[b] @ Q[b] : NN, M=32, N=512, K=256 (A packed)
    fgemm_kernel<2, false, 0, false, 0><<<dim3(8, 1, 64), 256, 0, stream>>>(
        WqQp, Q, nullptr, Up, nullptr, nullptr, nullptr,
        KP, Dn, Ln, Ln, Dn, (long)KP * Ln, (long)Ln * Dn, (long)KP * Dn);

    // g3. P = Uflat[2048,512] @ W_b : NN, MT=2 (512 blocks)
    fgemm_kernel<2, false, 0, false, 0><<<dim3(8, 64, 1), 256, 0, stream>>>(
        Up, W_b, nullptr, Pp, nullptr, nullptr, nullptr,
        Bn * KP, Dn, Dn, Dn, Dn, 0, 0, 0);

    // g5. Sout[b](rows<32) = ([W_v;0;P[b]] @ V[b]) : NN, M=64, N=1024, K=512
    //     A concat (ASRC=2: W_v fp32 + Pp packed); sv fused (EPI=2).
    fgemm_kernel<4, false, 2, true, 2><<<dim3(16, 1, 64), 256, 0, stream>>>(
        W_v, V, Pp, Soutp, w_hv, nullptr, sv,
        64, Mn, Dn, Dn, Mn, 0, (long)Dn * Mn, (long)KP * Mn);

    // g7 + smv fat kernel: x<8 -> R[b] = Sout[b] @ V[b]^T ; x>=8 -> smv pool
    g7smv_kernel<<<dim3(16, 1, 64), 256, 0, stream>>>(Soutp, V, Rp, sv, outv);

    // g8. G = Rflat[2048,512] @ W_b^T : NT, MT=2 (512 blocks)
    fgemm_kernel<2, true, 0, false, 0><<<dim3(8, 64, 1), 256, 0, stream>>>(
        Rp, W_b, nullptr, Gp, nullptr, nullptr, nullptr,
        Bn * KP, Dn, Dn, Dn, Dn, 0, 0, 0);

    // g9. Tq = G @ Q^T : NT, M=32, N=256, K=512; sq fused (EPI=3), X = WqQp
    fgemm_kernel<2, true, 3, false, 0><<<dim3(4, 1, 64), 256, 0, stream>>>(
        Gp, Q, nullptr, nullptr, w_hq, WqQp, sq,
        KP, Ln, Dn, Dn, Dn, (long)KP * Dn, (long)Ln * Dn, (long)KP * Ln);

    // smq: softmax + pool + broadcast out_q
    smq_out_kernel<<<dim3(8, Bn), 256, 0, stream>>>(sq, Q, outq);
}